// Round 8
// baseline (165.671 us; speedup 1.0000x reference)
//
#include <hip/hip_runtime.h>

typedef _Float16 f16;
typedef _Float16 half8 __attribute__((ext_vector_type(8)));
typedef float f32x4 __attribute__((ext_vector_type(4)));
typedef float f32x16 __attribute__((ext_vector_type(16)));
typedef unsigned u32x4 __attribute__((ext_vector_type(4)));

#define LDW 72  // padded LDS leading dim (f16): 144B row stride

// ---------------- K1: BatchNorm statistics -> per-block partials (r4 verbatim) ----------------
__global__ __launch_bounds__(256) void k_bnstats(const float* __restrict__ x, float* __restrict__ part){
    __shared__ float red[512];
    int t = threadIdx.x;
    int c = t & 63, rg = t >> 6;
    int rb = blockIdx.x * 64;
    float s = 0.f, s2 = 0.f;
    for(int r = rg; r < 64; r += 4){
        float v = x[(rb + r) * 64 + c];
        s += v; s2 += v * v;
    }
    red[t] = s; red[256 + t] = s2;
    __syncthreads();
    if(t < 128){
        int c2 = t & 63, h = t >> 6;
        float a = red[h * 256 + c2] + red[h * 256 + c2 + 64] + red[h * 256 + c2 + 128] + red[h * 256 + c2 + 192];
        part[blockIdx.x * 128 + t] = a;
    }
}

// ---------------- K2: partial-reduce + BN apply + QKV projections (r4 verbatim) ----------------
__global__ __launch_bounds__(256) void k_qkv(
    const float* __restrict__ x,
    const float* __restrict__ w1, const float* __restrict__ w2, const float* __restrict__ w3,
    const float* __restrict__ b1, const float* __restrict__ b2, const float* __restrict__ b3,
    const float* __restrict__ gamma, const float* __restrict__ beta,
    const float* __restrict__ part,
    f16* __restrict__ Q, f16* __restrict__ Kx, f16* __restrict__ Vt){
    __shared__ f16 wT[3 * 64 * LDW];
    __shared__ float sc[64], sh[64], bb[3][64];
    __shared__ float psum[128];
    int t = threadIdx.x;
    for(int i = t; i < 3 * 4096; i += 256){
        int j = i >> 12, e = i & 4095, k = e >> 6, n = e & 63;
        const float* wp = (j == 0) ? w1 : ((j == 1) ? w2 : w3);
        wT[j * 64 * LDW + n * LDW + k] = (f16)wp[e];
    }
    if(t < 128){
        float a0 = 0.f, a1 = 0.f, a2 = 0.f, a3 = 0.f;
        for(int b = 0; b < 256; b += 4){
            a0 += part[b * 128 + t];       a1 += part[(b + 1) * 128 + t];
            a2 += part[(b + 2) * 128 + t]; a3 += part[(b + 3) * 128 + t];
        }
        psum[t] = (a0 + a1) + (a2 + a3);
    }
    __syncthreads();
    if(t < 64){
        float mean = psum[t] * (1.f / 16384.f);
        float var  = psum[64 + t] * (1.f / 16384.f) - mean * mean;
        float s = gamma[t] * rsqrtf(var + 1e-5f);
        sc[t] = s;
        sh[t] = beta[t] - mean * s;
        bb[0][t] = b1[t]; bb[1][t] = b2[t]; bb[2][t] = b3[t];
    }
    __syncthreads();
    int w = t >> 6, lane = t & 63, quad = lane >> 4, l15 = lane & 15;
    int rowb = blockIdx.x * 64 + w * 16;
    int arow = rowb + l15;
    half8 a[2];
    #pragma unroll
    for(int kc = 0; kc < 2; kc++){
        f32x4 x0 = *(const f32x4*)&x[arow * 64 + kc * 32 + quad * 8];
        f32x4 x1 = *(const f32x4*)&x[arow * 64 + kc * 32 + quad * 8 + 4];
        half8 h;
        #pragma unroll
        for(int j = 0; j < 8; j++){
            int c = kc * 32 + quad * 8 + j;
            float xv = (j < 4) ? x0[j & 3] : x1[j & 3];
            h[j] = (f16)(xv * sc[c] + sh[c]);
        }
        a[kc] = h;
    }
    const f32x4 vzero = {0.f, 0.f, 0.f, 0.f};
    f32x4 acc[3][4];
    #pragma unroll
    for(int m = 0; m < 3; m++){
        #pragma unroll
        for(int nt = 0; nt < 4; nt++){
            acc[m][nt] = vzero;
            #pragma unroll
            for(int kc = 0; kc < 2; kc++){
                half8 bfr = *(half8*)&wT[m * 64 * LDW + (nt * 16 + l15) * LDW + kc * 32 + quad * 8];
                acc[m][nt] = __builtin_amdgcn_mfma_f32_16x16x32_f16(a[kc], bfr, acc[m][nt], 0, 0, 0);
            }
        }
    }
    const float qs = 0.18033688011112043f;  // log2(e)/8
    #pragma unroll
    for(int nt = 0; nt < 4; nt++){
        #pragma unroll
        for(int r = 0; r < 4; r++){
            int row = rowb + quad * 4 + r;
            int col = nt * 16 + l15;
            Q[row * 64 + col]  = (f16)((acc[0][nt][r] + bb[0][col]) * qs);
            Kx[row * 64 + col] = (f16)(acc[1][nt][r] + bb[1][col]);
            Vt[((row >> 12) * 64 + col) * 4096 + (row & 4095)] = (f16)(acc[2][nt][r] + bb[2][col]);
        }
    }
}

// ---------------- K3: streaming attention, direct-from-L2 MFMA fragments, NO LDS staging ----------------
// grid 1024: kq = bid&7 (K-eighth, XCD-pinned by round-robin dispatch), qg = bid>>3 (128-row Q groups).
// 32 Q-rows/wave; swapped-QK^T 32x32x16; in-register softmax (cvt_pkrtz + permlane32_swap).
// K+V (4MB) are L2-resident: fragments loaded straight from global. K-frags reg-double-buffered
// (needed at tile start); V-frags single-buffered, issued BEFORE QK^T and consumed after softmax (T14).
// Zero barriers / zero LDS traffic in the 16-tile sweep. Partials NORMALIZED (o/l) f16 + l f32.
__global__ __launch_bounds__(256, 3) void k_attn(
    const f16* __restrict__ Q, const f16* __restrict__ Kx, const f16* __restrict__ Vt,
    f16* __restrict__ Oph, float* __restrict__ lw){
    __shared__ float lred[4][32];
    int t = threadIdx.x;
    int kq = blockIdx.x & 7, qg = blockIdx.x >> 3;   // qg in [0,128)
    int b = qg >> 5;
    int w = t >> 6, lane = t & 63, l31 = lane & 31, hi = lane >> 5;
    int qrow0 = qg * 128 + w * 32;
    int kv0 = kq * 512;                              // this block's kv slice (within image)

    // Q fragments (B-operand): lane holds qrow = qrow0+l31, d-elems dc*16 + hi*8 .. +7
    half8 aq[4];
    #pragma unroll
    for(int dc = 0; dc < 4; dc++)
        aq[dc] = *(const half8*)&Q[(qrow0 + l31) * 64 + dc * 16 + hi * 8];

    // fragment source pointers (f16 element units)
    const f16* kp  = Kx + (size_t)(b * 4096 + kv0 + l31) * 64 + hi * 8;     // +dc*16 imm
    const f16* vp0 = Vt + (size_t)(b * 64 + l31) * 4096 + kv0 + hi * 8;     // d-rows 0..31, +kc*16 imm
    const f16* vp1 = Vt + (size_t)(b * 64 + 32 + l31) * 4096 + kv0 + hi * 8;// d-rows 32..63

    half8 kf[2][4];   // K fragments, double-buffered
    half8 vf[2][2];   // V fragments [kc][dt], single-buffered (latency hidden under QK+softmax)
    #pragma unroll
    for(int dc = 0; dc < 4; dc++) kf[0][dc] = *(const half8*)(kp + dc * 16);
    kp += 32 * 64;

    f32x16 o[2];
    #pragma unroll
    for(int dt = 0; dt < 2; dt++)
        #pragma unroll
        for(int r = 0; r < 16; r++) o[dt][r] = 0.f;
    float lp = 0.f;

    #pragma unroll
    for(int j = 0; j < 16; j++){                     // 16 tiles of 32 kv rows = 512
        const int cur = j & 1;
        // V fragments for THIS tile — issued first, consumed after softmax (~200cy later)
        #pragma unroll
        for(int kc = 0; kc < 2; kc++){
            vf[kc][0] = *(const half8*)(vp0 + kc * 16);
            vf[kc][1] = *(const half8*)(vp1 + kc * 16);
        }
        vp0 += 32; vp1 += 32;
        // K fragments for NEXT tile
        if(j < 15){
            #pragma unroll
            for(int dc = 0; dc < 4; dc++) kf[cur ^ 1][dc] = *(const half8*)(kp + dc * 16);
            kp += 32 * 64;
        }
        // QK^T (swapped): S^T = mfma(A=K, B=Q); lane's 16 values belong to qrow qrow0+l31,
        // kcol_local = (r&3)+8*(r>>2)+4*hi
        f32x16 s;
        #pragma unroll
        for(int r = 0; r < 16; r++) s[r] = 0.f;
        #pragma unroll
        for(int dc = 0; dc < 4; dc++)
            s = __builtin_amdgcn_mfma_f32_32x32x16_f16(kf[cur][dc], aq[dc], s, 0, 0, 0);
        float pf[16], ls = 0.f;
        #pragma unroll
        for(int r = 0; r < 16; r++){
            float p = __builtin_amdgcn_exp2f(fminf(s[r], 15.f));
            pf[r] = p; ls += p;
        }
        lp += ls;
        unsigned wv[4][2];
        #pragma unroll
        for(int g = 0; g < 4; g++){
            wv[g][0] = __builtin_bit_cast(unsigned, __builtin_amdgcn_cvt_pkrtz(pf[4*g+0], pf[4*g+1]));
            wv[g][1] = __builtin_bit_cast(unsigned, __builtin_amdgcn_cvt_pkrtz(pf[4*g+2], pf[4*g+3]));
        }
        // A-frag chunk kc (16 kcols): lane-half hi needs kcols kc*16+hi*8..+7
        #pragma unroll
        for(int kc = 0; kc < 2; kc++){
            unsigned x0 = wv[2*kc][0], y0 = wv[2*kc+1][0];
            unsigned x1 = wv[2*kc][1], y1 = wv[2*kc+1][1];
            asm("v_permlane32_swap_b32 %0, %1" : "+v"(x0), "+v"(y0));
            asm("v_permlane32_swap_b32 %0, %1" : "+v"(x1), "+v"(y1));
            u32x4 pw = {x0, x1, y0, y1};
            half8 pa = __builtin_bit_cast(half8, pw);
            #pragma unroll
            for(int dt = 0; dt < 2; dt++)
                o[dt] = __builtin_amdgcn_mfma_f32_32x32x16_f16(pa, vf[kc][dt], o[dt], 0, 0, 0);
        }
    }
    // row sums: lanes l and l+32 hold the same qrow
    {
        float v = lp + __shfl_xor(lp, 32);
        if(hi == 0){
            int row = qrow0 + l31;
            lw[kq * 16384 + row] = v;
            lred[w][l31] = __builtin_amdgcn_rcpf(v);
        }
    }
    __builtin_amdgcn_s_waitcnt(0);   // lgkmcnt(0): lred visible to whole wave (single wave writes/reads)
    // O layout: lane holds d = dt*32+l31; qrow = (r&3)+8*(r>>2)+4*hi
    #pragma unroll
    for(int r = 0; r < 16; r++){
        int qrl = (r & 3) + 8 * (r >> 2) + 4 * hi;
        float inv = lred[w][qrl];
        int row = qrow0 + qrl;
        #pragma unroll
        for(int dt = 0; dt < 2; dt++)
            Oph[kq * 1048576 + row * 64 + dt * 32 + l31] = (f16)(o[dt][r] * inv);
    }
}

// ---------------- K4: weighted merge of normalized partials, W4 projection + bias + residual (r4 verbatim) ----
__global__ __launch_bounds__(256) void k_merge(
    const f16* __restrict__ Oph, const float* __restrict__ lw,
    const float* __restrict__ w4, const float* __restrict__ b4,
    const float* __restrict__ x, float* __restrict__ out){
    __shared__ f16 Om[64 * LDW];
    __shared__ f16 wT[64 * LDW];
    __shared__ float b4f[64];
    int t = threadIdx.x;
    int rb = blockIdx.x * 64;
    for(int i = t; i < 4096; i += 256){
        int k = i >> 6, n = i & 63;
        wT[n * LDW + k] = (f16)w4[i];
    }
    if(t < 64) b4f[t] = b4[t];
    for(int i = t; i < 512; i += 256){
        int row = i >> 3, c8 = i & 7;
        int gr = rb + row;
        float num[8] = {0.f,0.f,0.f,0.f,0.f,0.f,0.f,0.f};
        float den = 0.f;
        #pragma unroll
        for(int s = 0; s < 8; s++){
            float li = lw[s * 16384 + gr];
            half8 ov = *(const half8*)&Oph[s * 1048576 + gr * 64 + c8 * 8];
            #pragma unroll
            for(int j = 0; j < 8; j++) num[j] += li * (float)ov[j];
            den += li;
        }
        float invd = 1.f / den;
        #pragma unroll
        for(int j = 0; j < 8; j++) Om[row * LDW + c8 * 8 + j] = (f16)(num[j] * invd);
    }
    __syncthreads();
    int w = t >> 6, lane = t & 63, quad = lane >> 4, l15 = lane & 15;
    half8 a[2];
    #pragma unroll
    for(int kc = 0; kc < 2; kc++)
        a[kc] = *(half8*)&Om[(w * 16 + l15) * LDW + kc * 32 + quad * 8];
    #pragma unroll
    for(int nt = 0; nt < 4; nt++){
        f32x4 y = {0.f, 0.f, 0.f, 0.f};
        #pragma unroll
        for(int kc = 0; kc < 2; kc++){
            half8 bfr = *(half8*)&wT[(nt * 16 + l15) * LDW + kc * 32 + quad * 8];
            y = __builtin_amdgcn_mfma_f32_16x16x32_f16(a[kc], bfr, y, 0, 0, 0);
        }
        #pragma unroll
        for(int r = 0; r < 4; r++){
            int row = rb + w * 16 + quad * 4 + r;
            int col = nt * 16 + l15;
            out[row * 64 + col] = y[r] + b4f[col] + x[row * 64 + col];
        }
    }
}

extern "C" void kernel_launch(void* const* d_in, const int* in_sizes, int n_in,
                              void* d_out, int out_size, void* d_ws, size_t ws_size,
                              hipStream_t stream){
    (void)in_sizes; (void)n_in; (void)out_size; (void)ws_size;
    const float* x  = (const float*)d_in[0];
    const float* w1 = (const float*)d_in[1];
    const float* w2 = (const float*)d_in[2];
    const float* w3 = (const float*)d_in[3];
    const float* w4 = (const float*)d_in[4];
    const float* b1 = (const float*)d_in[5];
    const float* b2 = (const float*)d_in[6];
    const float* b3 = (const float*)d_in[7];
    const float* b4 = (const float*)d_in[8];
    const float* gm = (const float*)d_in[9];
    const float* bt = (const float*)d_in[10];
    char* ws = (char*)d_ws;
    f16* Q    = (f16*)(ws);
    f16* Kx   = (f16*)(ws + (size_t)(2u << 20));
    f16* Vt   = (f16*)(ws + (size_t)(4u << 20));
    float* part = (float*)(ws + (size_t)(6u << 20));                         // 256 x 128 f32 = 128KB
    f16* Oph  = (f16*)(ws + (size_t)(8u << 20));                             // 8 x 2MB (f16, normalized)
    float* lwp = (float*)(ws + (size_t)(24u << 20));                         // 8 x 64KB

    hipLaunchKernelGGL(k_bnstats, dim3(256),  dim3(256), 0, stream, x, part);
    hipLaunchKernelGGL(k_qkv,     dim3(256),  dim3(256), 0, stream, x, w1, w2, w3, b1, b2, b3, gm, bt, part, Q, Kx, Vt);
    hipLaunchKernelGGL(k_attn,    dim3(1024), dim3(256), 0, stream, Q, Kx, Vt, Oph, lwp);
    hipLaunchKernelGGL(k_merge,   dim3(256),  dim3(256), 0, stream, Oph, lwp, w4, b4, x, (float*)d_out);
}

// Round 10
// 139.518 us; speedup vs baseline: 1.1875x; 1.1875x over previous
//
#include <hip/hip_runtime.h>

typedef _Float16 f16;
typedef _Float16 half8 __attribute__((ext_vector_type(8)));
typedef float f32x4 __attribute__((ext_vector_type(4)));
typedef float f32x16 __attribute__((ext_vector_type(16)));
typedef unsigned u32x4 __attribute__((ext_vector_type(4)));

#define LDW 72  // padded LDS leading dim (f16): 144B row stride

// ---------------- K1: BatchNorm statistics -> per-block partials (r4 verbatim) ----------------
__global__ __launch_bounds__(256) void k_bnstats(const float* __restrict__ x, float* __restrict__ part){
    __shared__ float red[512];
    int t = threadIdx.x;
    int c = t & 63, rg = t >> 6;
    int rb = blockIdx.x * 64;
    float s = 0.f, s2 = 0.f;
    for(int r = rg; r < 64; r += 4){
        float v = x[(rb + r) * 64 + c];
        s += v; s2 += v * v;
    }
    red[t] = s; red[256 + t] = s2;
    __syncthreads();
    if(t < 128){
        int c2 = t & 63, h = t >> 6;
        float a = red[h * 256 + c2] + red[h * 256 + c2 + 64] + red[h * 256 + c2 + 128] + red[h * 256 + c2 + 192];
        part[blockIdx.x * 128 + t] = a;
    }
}

// ---------------- K2: partial-reduce + BN apply + QKV projections (r4 verbatim) ----------------
__global__ __launch_bounds__(256) void k_qkv(
    const float* __restrict__ x,
    const float* __restrict__ w1, const float* __restrict__ w2, const float* __restrict__ w3,
    const float* __restrict__ b1, const float* __restrict__ b2, const float* __restrict__ b3,
    const float* __restrict__ gamma, const float* __restrict__ beta,
    const float* __restrict__ part,
    f16* __restrict__ Q, f16* __restrict__ Kx, f16* __restrict__ Vt){
    __shared__ f16 wT[3 * 64 * LDW];
    __shared__ float sc[64], sh[64], bb[3][64];
    __shared__ float psum[128];
    int t = threadIdx.x;
    for(int i = t; i < 3 * 4096; i += 256){
        int j = i >> 12, e = i & 4095, k = e >> 6, n = e & 63;
        const float* wp = (j == 0) ? w1 : ((j == 1) ? w2 : w3);
        wT[j * 64 * LDW + n * LDW + k] = (f16)wp[e];
    }
    if(t < 128){
        float a0 = 0.f, a1 = 0.f, a2 = 0.f, a3 = 0.f;
        for(int b = 0; b < 256; b += 4){
            a0 += part[b * 128 + t];       a1 += part[(b + 1) * 128 + t];
            a2 += part[(b + 2) * 128 + t]; a3 += part[(b + 3) * 128 + t];
        }
        psum[t] = (a0 + a1) + (a2 + a3);
    }
    __syncthreads();
    if(t < 64){
        float mean = psum[t] * (1.f / 16384.f);
        float var  = psum[64 + t] * (1.f / 16384.f) - mean * mean;
        float s = gamma[t] * rsqrtf(var + 1e-5f);
        sc[t] = s;
        sh[t] = beta[t] - mean * s;
        bb[0][t] = b1[t]; bb[1][t] = b2[t]; bb[2][t] = b3[t];
    }
    __syncthreads();
    int w = t >> 6, lane = t & 63, quad = lane >> 4, l15 = lane & 15;
    int rowb = blockIdx.x * 64 + w * 16;
    int arow = rowb + l15;
    half8 a[2];
    #pragma unroll
    for(int kc = 0; kc < 2; kc++){
        f32x4 x0 = *(const f32x4*)&x[arow * 64 + kc * 32 + quad * 8];
        f32x4 x1 = *(const f32x4*)&x[arow * 64 + kc * 32 + quad * 8 + 4];
        half8 h;
        #pragma unroll
        for(int j = 0; j < 8; j++){
            int c = kc * 32 + quad * 8 + j;
            float xv = (j < 4) ? x0[j & 3] : x1[j & 3];
            h[j] = (f16)(xv * sc[c] + sh[c]);
        }
        a[kc] = h;
    }
    const f32x4 vzero = {0.f, 0.f, 0.f, 0.f};
    f32x4 acc[3][4];
    #pragma unroll
    for(int m = 0; m < 3; m++){
        #pragma unroll
        for(int nt = 0; nt < 4; nt++){
            acc[m][nt] = vzero;
            #pragma unroll
            for(int kc = 0; kc < 2; kc++){
                half8 bfr = *(half8*)&wT[m * 64 * LDW + (nt * 16 + l15) * LDW + kc * 32 + quad * 8];
                acc[m][nt] = __builtin_amdgcn_mfma_f32_16x16x32_f16(a[kc], bfr, acc[m][nt], 0, 0, 0);
            }
        }
    }
    const float qs = 0.18033688011112043f;  // log2(e)/8
    #pragma unroll
    for(int nt = 0; nt < 4; nt++){
        #pragma unroll
        for(int r = 0; r < 4; r++){
            int row = rowb + quad * 4 + r;
            int col = nt * 16 + l15;
            Q[row * 64 + col]  = (f16)((acc[0][nt][r] + bb[0][col]) * qs);
            Kx[row * 64 + col] = (f16)(acc[1][nt][r] + bb[1][col]);
            Vt[((row >> 12) * 64 + col) * 4096 + (row & 4095)] = (f16)(acc[2][nt][r] + bb[2][col]);
        }
    }
}

// ---------------- K3: streaming attention, 2-tile-deep register prefetch ----------------
// grid 1024: kq = bid&7 (K-eighth), qg = bid>>3 (128-row Q groups). 4 blocks/CU, 16 waves/CU.
// 32 Q-rows/wave; swapped-QK^T 32x32x16; in-register softmax (cvt_pkrtz + permlane32_swap).
// Staging pipeline depth 2: at tile j issue loads for j+2; write j+1's data (loaded a full
// tile earlier -> vmcnt satisfied, no drain stall at the pre-barrier write). Full unroll keeps
// both prefetch register sets statically indexed. Partials NORMALIZED (o/l) f16 + l f32.
__global__ __launch_bounds__(256, 4) void k_attn(
    const f16* __restrict__ Q, const f16* __restrict__ Kx, const f16* __restrict__ Vt,
    f16* __restrict__ Oph, float* __restrict__ lw){
    __shared__ f16 KV[2][2 * 64 * LDW];
    __shared__ float lred[4][32];
    int t = threadIdx.x;
    int kq = blockIdx.x & 7, qg = blockIdx.x >> 3;   // qg in [0,128)
    int b = qg >> 5;
    int w = t >> 6, lane = t & 63, l31 = lane & 31, hi = lane >> 5;
    int qrow0 = qg * 128 + w * 32;
    const int BUF = 2 * 64 * LDW;

    // Q fragments (B-operand): lane holds qrow = qrow0+l31, d-elems dc*16 + hi*8 .. +7
    half8 aq[4];
    #pragma unroll
    for(int dc = 0; dc < 4; dc++)
        aq[dc] = *(const half8*)&Q[(qrow0 + l31) * 64 + dc * 16 + hi * 8];

    // staging: 1024 x 16B chunks per 64-row tile (512 K + 512 V^T); 4 chunks/thread
    const f16* gsrc[4];
    int loff[4], gstep[4];
    #pragma unroll
    for(int i = 0; i < 4; i++){
        int idx = t + i * 256;
        int rr = (idx >> 3) & 63, c8 = idx & 7, kt0 = kq * 8;
        if(idx < 512){
            loff[i] = rr * LDW + c8 * 8;
            gsrc[i] = &Kx[(b * 4096 + kt0 * 64 + rr) * 64 + c8 * 8];
            gstep[i] = 64 * 64;
        } else {
            loff[i] = 64 * LDW + rr * LDW + c8 * 8;
            gsrc[i] = &Vt[(b * 64 + rr) * 4096 + kt0 * 64 + c8 * 8];
            gstep[i] = 64;
        }
    }
    // prologue: tile0 -> LDS buf0; tile1 -> pA (stays in flight/regs until end of j=0)
    half8 pA[4], pB[4];
    #pragma unroll
    for(int i = 0; i < 4; i++){ pA[i] = *(const half8*)gsrc[i]; gsrc[i] += gstep[i]; }
    #pragma unroll
    for(int i = 0; i < 4; i++) *(half8*)&KV[0][loff[i]] = pA[i];
    #pragma unroll
    for(int i = 0; i < 4; i++){ pA[i] = *(const half8*)gsrc[i]; gsrc[i] += gstep[i]; }

    f32x16 o[2];
    #pragma unroll
    for(int dt = 0; dt < 2; dt++)
        #pragma unroll
        for(int r = 0; r < 16; r++) o[dt][r] = 0.f;
    float lp = 0.f;

    __syncthreads();
    #pragma unroll
    for(int j = 0; j < 8; j++){
        const int cur = j & 1;
        // issue loads for tile j+2 into the free register set (consumed at end of tile j+1)
        if(j < 6){
            if((j & 1) == 0){
                #pragma unroll
                for(int i = 0; i < 4; i++){ pB[i] = *(const half8*)gsrc[i]; gsrc[i] += gstep[i]; }
            } else {
                #pragma unroll
                for(int i = 0; i < 4; i++){ pA[i] = *(const half8*)gsrc[i]; gsrc[i] += gstep[i]; }
            }
        }
        const f16* Kb = &KV[0][0] + cur * BUF;
        const f16* Vb = Kb + 64 * LDW;
        #pragma unroll
        for(int kt = 0; kt < 2; kt++){
            // K fragments (A-operand): lane holds kcol = kt*32+l31, d-elems dc*16 + hi*8
            half8 ak[4];
            #pragma unroll
            for(int dc = 0; dc < 4; dc++)
                ak[dc] = *(const half8*)&Kb[(kt * 32 + l31) * LDW + dc * 16 + hi * 8];
            // V fragments (B-operand): lane holds d = dt*32+l31, kcols kt*32 + kc*16 + hi*8
            half8 vb[2][2];
            #pragma unroll
            for(int kc = 0; kc < 2; kc++)
                #pragma unroll
                for(int dt = 0; dt < 2; dt++)
                    vb[kc][dt] = *(const half8*)&Vb[(dt * 32 + l31) * LDW + kt * 32 + kc * 16 + hi * 8];
            f32x16 s;
            #pragma unroll
            for(int r = 0; r < 16; r++) s[r] = 0.f;
            #pragma unroll
            for(int dc = 0; dc < 4; dc++)
                s = __builtin_amdgcn_mfma_f32_32x32x16_f16(ak[dc], aq[dc], s, 0, 0, 0);
            // S^T layout: lane's 16 values belong to qrow = qrow0+l31; kcol_local = (r&3)+8*(r>>2)+4*hi
            float pf[16], ls = 0.f;
            #pragma unroll
            for(int r = 0; r < 16; r++){
                float p = __builtin_amdgcn_exp2f(fminf(s[r], 15.f));
                pf[r] = p; ls += p;
            }
            lp += ls;
            unsigned wv[4][2];
            #pragma unroll
            for(int g = 0; g < 4; g++){
                wv[g][0] = __builtin_bit_cast(unsigned, __builtin_amdgcn_cvt_pkrtz(pf[4*g+0], pf[4*g+1]));
                wv[g][1] = __builtin_bit_cast(unsigned, __builtin_amdgcn_cvt_pkrtz(pf[4*g+2], pf[4*g+3]));
            }
            // A-frag chunk kc (16 kcols): lane-half hi needs kcols kc*16+hi*8..+7
            #pragma unroll
            for(int kc = 0; kc < 2; kc++){
                unsigned x0 = wv[2*kc][0], y0 = wv[2*kc+1][0];
                unsigned x1 = wv[2*kc][1], y1 = wv[2*kc+1][1];
                asm("v_permlane32_swap_b32 %0, %1" : "+v"(x0), "+v"(y0));
                asm("v_permlane32_swap_b32 %0, %1" : "+v"(x1), "+v"(y1));
                u32x4 pw = {x0, x1, y0, y1};
                half8 pa = __builtin_bit_cast(half8, pw);
                #pragma unroll
                for(int dt = 0; dt < 2; dt++)
                    o[dt] = __builtin_amdgcn_mfma_f32_32x32x16_f16(pa, vb[kc][dt], o[dt], 0, 0, 0);
            }
        }
        // write tile j+1 (loaded one full tile ago -> no vmcnt stall) into the spare buffer
        if(j < 7){
            f16* wb = &KV[0][0] + (cur ^ 1) * BUF;
            if((j & 1) == 0){
                #pragma unroll
                for(int i = 0; i < 4; i++) *(half8*)(wb + loff[i]) = pA[i];
            } else {
                #pragma unroll
                for(int i = 0; i < 4; i++) *(half8*)(wb + loff[i]) = pB[i];
            }
        }
        __syncthreads();
    }
    // row sums: lanes l and l+32 hold the same qrow
    {
        float v = lp + __shfl_xor(lp, 32);
        if(hi == 0){
            int row = qrow0 + l31;
            lw[kq * 16384 + row] = v;
            lred[w][l31] = __builtin_amdgcn_rcpf(v);
        }
    }
    // O layout: lane holds d = dt*32+l31; qrow = (r&3)+8*(r>>2)+4*hi
    #pragma unroll
    for(int r = 0; r < 16; r++){
        int qrl = (r & 3) + 8 * (r >> 2) + 4 * hi;
        float inv = lred[w][qrl];
        int row = qrow0 + qrl;
        #pragma unroll
        for(int dt = 0; dt < 2; dt++)
            Oph[kq * 1048576 + row * 64 + dt * 32 + l31] = (f16)(o[dt][r] * inv);
    }
}

// ---------------- K4: weighted merge of normalized partials, W4 projection + bias + residual (r4 verbatim) ----
__global__ __launch_bounds__(256) void k_merge(
    const f16* __restrict__ Oph, const float* __restrict__ lw,
    const float* __restrict__ w4, const float* __restrict__ b4,
    const float* __restrict__ x, float* __restrict__ out){
    __shared__ f16 Om[64 * LDW];
    __shared__ f16 wT[64 * LDW];
    __shared__ float b4f[64];
    int t = threadIdx.x;
    int rb = blockIdx.x * 64;
    for(int i = t; i < 4096; i += 256){
        int k = i >> 6, n = i & 63;
        wT[n * LDW + k] = (f16)w4[i];
    }
    if(t < 64) b4f[t] = b4[t];
    for(int i = t; i < 512; i += 256){
        int row = i >> 3, c8 = i & 7;
        int gr = rb + row;
        float num[8] = {0.f,0.f,0.f,0.f,0.f,0.f,0.f,0.f};
        float den = 0.f;
        #pragma unroll
        for(int s = 0; s < 8; s++){
            float li = lw[s * 16384 + gr];
            half8 ov = *(const half8*)&Oph[s * 1048576 + gr * 64 + c8 * 8];
            #pragma unroll
            for(int j = 0; j < 8; j++) num[j] += li * (float)ov[j];
            den += li;
        }
        float invd = 1.f / den;
        #pragma unroll
        for(int j = 0; j < 8; j++) Om[row * LDW + c8 * 8 + j] = (f16)(num[j] * invd);
    }
    __syncthreads();
    int w = t >> 6, lane = t & 63, quad = lane >> 4, l15 = lane & 15;
    half8 a[2];
    #pragma unroll
    for(int kc = 0; kc < 2; kc++)
        a[kc] = *(half8*)&Om[(w * 16 + l15) * LDW + kc * 32 + quad * 8];
    #pragma unroll
    for(int nt = 0; nt < 4; nt++){
        f32x4 y = {0.f, 0.f, 0.f, 0.f};
        #pragma unroll
        for(int kc = 0; kc < 2; kc++){
            half8 bfr = *(half8*)&wT[(nt * 16 + l15) * LDW + kc * 32 + quad * 8];
            y = __builtin_amdgcn_mfma_f32_16x16x32_f16(a[kc], bfr, y, 0, 0, 0);
        }
        #pragma unroll
        for(int r = 0; r < 4; r++){
            int row = rb + w * 16 + quad * 4 + r;
            int col = nt * 16 + l15;
            out[row * 64 + col] = y[r] + b4f[col] + x[row * 64 + col];
        }
    }
}

extern "C" void kernel_launch(void* const* d_in, const int* in_sizes, int n_in,
                              void* d_out, int out_size, void* d_ws, size_t ws_size,
                              hipStream_t stream){
    (void)in_sizes; (void)n_in; (void)out_size; (void)ws_size;
    const float* x  = (const float*)d_in[0];
    const float* w1 = (const float*)d_in[1];
    const float* w2 = (const float*)d_in[2];
    const float* w3 = (const float*)d_in[3];
    const float* w4 = (const float*)d_in[4];
    const float* b1 = (const float*)d_in[5];
    const float* b2 = (const float*)d_in[6];
    const float* b3 = (const float*)d_in[7];
    const float* b4 = (const float*)d_in[8];
    const float* gm = (const float*)d_in[9];
    const float* bt = (const float*)d_in[10];
    char* ws = (char*)d_ws;
    f16* Q    = (f16*)(ws);
    f16* Kx   = (f16*)(ws + (size_t)(2u << 20));
    f16* Vt   = (f16*)(ws + (size_t)(4u << 20));
    float* part = (float*)(ws + (size_t)(6u << 20));                         // 256 x 128 f32 = 128KB
    f16* Oph  = (f16*)(ws + (size_t)(8u << 20));                             // 8 x 2MB (f16, normalized)
    float* lwp = (float*)(ws + (size_t)(24u << 20));                         // 8 x 64KB

    hipLaunchKernelGGL(k_bnstats, dim3(256),  dim3(256), 0, stream, x, part);
    hipLaunchKernelGGL(k_qkv,     dim3(256),  dim3(256), 0, stream, x, w1, w2, w3, b1, b2, b3, gm, bt, part, Q, Kx, Vt);
    hipLaunchKernelGGL(k_attn,    dim3(1024), dim3(256), 0, stream, Q, Kx, Vt, Oph, lwp);
    hipLaunchKernelGGL(k_merge,   dim3(256),  dim3(256), 0, stream, Oph, lwp, w4, b4, x, (float*)d_out);
}

// Round 11
// 128.728 us; speedup vs baseline: 1.2870x; 1.0838x over previous
//
#include <hip/hip_runtime.h>

typedef _Float16 f16;
typedef _Float16 half8 __attribute__((ext_vector_type(8)));
typedef float f32x4 __attribute__((ext_vector_type(4)));
typedef float f32x16 __attribute__((ext_vector_type(16)));
typedef unsigned u32x4 __attribute__((ext_vector_type(4)));

#define LDW 72  // padded LDS leading dim (f16): 144B row stride

// ---------------- K1: BatchNorm statistics -> per-block partials (r4 verbatim) ----------------
__global__ __launch_bounds__(256) void k_bnstats(const float* __restrict__ x, float* __restrict__ part){
    __shared__ float red[512];
    int t = threadIdx.x;
    int c = t & 63, rg = t >> 6;
    int rb = blockIdx.x * 64;
    float s = 0.f, s2 = 0.f;
    for(int r = rg; r < 64; r += 4){
        float v = x[(rb + r) * 64 + c];
        s += v; s2 += v * v;
    }
    red[t] = s; red[256 + t] = s2;
    __syncthreads();
    if(t < 128){
        int c2 = t & 63, h = t >> 6;
        float a = red[h * 256 + c2] + red[h * 256 + c2 + 64] + red[h * 256 + c2 + 128] + red[h * 256 + c2 + 192];
        part[blockIdx.x * 128 + t] = a;
    }
}

// ---------------- K2: partial-reduce + BN apply + QKV projections (r4 verbatim) ----------------
__global__ __launch_bounds__(256) void k_qkv(
    const float* __restrict__ x,
    const float* __restrict__ w1, const float* __restrict__ w2, const float* __restrict__ w3,
    const float* __restrict__ b1, const float* __restrict__ b2, const float* __restrict__ b3,
    const float* __restrict__ gamma, const float* __restrict__ beta,
    const float* __restrict__ part,
    f16* __restrict__ Q, f16* __restrict__ Kx, f16* __restrict__ Vt){
    __shared__ f16 wT[3 * 64 * LDW];
    __shared__ float sc[64], sh[64], bb[3][64];
    __shared__ float psum[128];
    int t = threadIdx.x;
    for(int i = t; i < 3 * 4096; i += 256){
        int j = i >> 12, e = i & 4095, k = e >> 6, n = e & 63;
        const float* wp = (j == 0) ? w1 : ((j == 1) ? w2 : w3);
        wT[j * 64 * LDW + n * LDW + k] = (f16)wp[e];
    }
    if(t < 128){
        float a0 = 0.f, a1 = 0.f, a2 = 0.f, a3 = 0.f;
        for(int b = 0; b < 256; b += 4){
            a0 += part[b * 128 + t];       a1 += part[(b + 1) * 128 + t];
            a2 += part[(b + 2) * 128 + t]; a3 += part[(b + 3) * 128 + t];
        }
        psum[t] = (a0 + a1) + (a2 + a3);
    }
    __syncthreads();
    if(t < 64){
        float mean = psum[t] * (1.f / 16384.f);
        float var  = psum[64 + t] * (1.f / 16384.f) - mean * mean;
        float s = gamma[t] * rsqrtf(var + 1e-5f);
        sc[t] = s;
        sh[t] = beta[t] - mean * s;
        bb[0][t] = b1[t]; bb[1][t] = b2[t]; bb[2][t] = b3[t];
    }
    __syncthreads();
    int w = t >> 6, lane = t & 63, quad = lane >> 4, l15 = lane & 15;
    int rowb = blockIdx.x * 64 + w * 16;
    int arow = rowb + l15;
    half8 a[2];
    #pragma unroll
    for(int kc = 0; kc < 2; kc++){
        f32x4 x0 = *(const f32x4*)&x[arow * 64 + kc * 32 + quad * 8];
        f32x4 x1 = *(const f32x4*)&x[arow * 64 + kc * 32 + quad * 8 + 4];
        half8 h;
        #pragma unroll
        for(int j = 0; j < 8; j++){
            int c = kc * 32 + quad * 8 + j;
            float xv = (j < 4) ? x0[j & 3] : x1[j & 3];
            h[j] = (f16)(xv * sc[c] + sh[c]);
        }
        a[kc] = h;
    }
    const f32x4 vzero = {0.f, 0.f, 0.f, 0.f};
    f32x4 acc[3][4];
    #pragma unroll
    for(int m = 0; m < 3; m++){
        #pragma unroll
        for(int nt = 0; nt < 4; nt++){
            acc[m][nt] = vzero;
            #pragma unroll
            for(int kc = 0; kc < 2; kc++){
                half8 bfr = *(half8*)&wT[m * 64 * LDW + (nt * 16 + l15) * LDW + kc * 32 + quad * 8];
                acc[m][nt] = __builtin_amdgcn_mfma_f32_16x16x32_f16(a[kc], bfr, acc[m][nt], 0, 0, 0);
            }
        }
    }
    const float qs = 0.18033688011112043f;  // log2(e)/8
    #pragma unroll
    for(int nt = 0; nt < 4; nt++){
        #pragma unroll
        for(int r = 0; r < 4; r++){
            int row = rowb + quad * 4 + r;
            int col = nt * 16 + l15;
            Q[row * 64 + col]  = (f16)((acc[0][nt][r] + bb[0][col]) * qs);
            Kx[row * 64 + col] = (f16)(acc[1][nt][r] + bb[1][col]);
            Vt[((row >> 12) * 64 + col) * 4096 + (row & 4095)] = (f16)(acc[2][nt][r] + bb[2][col]);
        }
    }
}

// ---------------- K3: streaming attention, spill-free (128-VGPR cap, halved softmax live range) ---------
// grid 1024: kq = bid&7 (K-eighth), qg = bid>>3 (128-row Q groups). 2 blocks/CU (no VGPR spill:
// r10 showed launch_bounds(256,4) caps at 64 VGPR -> ~78MB scratch traffic; (256,2) caps at 128).
// 32 Q-rows/wave; swapped-QK^T 32x32x16; in-register softmax processed in TWO 8-element halves
// (pf/wv live ranges halved; kc=h A-chunk needs only pf[8h..8h+7]). 1-deep register prefetch.
__global__ __launch_bounds__(256, 2) void k_attn(
    const f16* __restrict__ Q, const f16* __restrict__ Kx, const f16* __restrict__ Vt,
    f16* __restrict__ Oph, float* __restrict__ lw){
    __shared__ f16 KV[2][2 * 64 * LDW];
    __shared__ float lred[4][32];
    int t = threadIdx.x;
    int kq = blockIdx.x & 7, qg = blockIdx.x >> 3;   // qg in [0,128)
    int b = qg >> 5;
    int w = t >> 6, lane = t & 63, l31 = lane & 31, hi = lane >> 5;
    int qrow0 = qg * 128 + w * 32;
    const int BUF = 2 * 64 * LDW;

    // Q fragments (B-operand): lane holds qrow = qrow0+l31, d-elems dc*16 + hi*8 .. +7
    half8 aq[4];
    #pragma unroll
    for(int dc = 0; dc < 4; dc++)
        aq[dc] = *(const half8*)&Q[(qrow0 + l31) * 64 + dc * 16 + hi * 8];

    // staging: 1024 x 16B chunks per 64-row tile (512 K + 512 V^T); 4 chunks/thread.
    // i=0,1 -> K chunks (idx<512, step 4096); i=2,3 -> V^T chunks (step 64). gstep compile-time.
    const f16* gsrc[4];
    int loff[4];
    #pragma unroll
    for(int i = 0; i < 4; i++){
        int idx = t + i * 256;
        int rr = (idx >> 3) & 63, c8 = idx & 7, kt0 = kq * 8;
        if(i < 2){
            loff[i] = rr * LDW + c8 * 8;
            gsrc[i] = &Kx[(b * 4096 + kt0 * 64 + rr) * 64 + c8 * 8];
        } else {
            loff[i] = 64 * LDW + rr * LDW + c8 * 8;
            gsrc[i] = &Vt[(b * 64 + rr) * 4096 + kt0 * 64 + c8 * 8];
        }
    }
    half8 pre[4];
    #pragma unroll
    for(int i = 0; i < 4; i++){ pre[i] = *(const half8*)gsrc[i]; gsrc[i] += (i < 2) ? 4096 : 64; }
    #pragma unroll
    for(int i = 0; i < 4; i++) *(half8*)&KV[0][loff[i]] = pre[i];

    f32x16 o[2];
    #pragma unroll
    for(int dt = 0; dt < 2; dt++)
        #pragma unroll
        for(int r = 0; r < 16; r++) o[dt][r] = 0.f;
    float lp = 0.f;

    __syncthreads();
    int cur = 0;
    for(int j = 0; j < 8; j++){
        if(j < 7){  // issue next-tile global loads early; consumed at tile end (T14)
            #pragma unroll
            for(int i = 0; i < 4; i++){ pre[i] = *(const half8*)gsrc[i]; gsrc[i] += (i < 2) ? 4096 : 64; }
        }
        const f16* Kb = &KV[0][0] + cur * BUF;
        const f16* Vb = Kb + 64 * LDW;
        #pragma unroll
        for(int kt = 0; kt < 2; kt++){
            // K fragments (A-operand): lane holds kcol = kt*32+l31, d-elems dc*16 + hi*8
            half8 ak[4];
            #pragma unroll
            for(int dc = 0; dc < 4; dc++)
                ak[dc] = *(const half8*)&Kb[(kt * 32 + l31) * LDW + dc * 16 + hi * 8];
            f32x16 s;
            #pragma unroll
            for(int r = 0; r < 16; r++) s[r] = 0.f;
            #pragma unroll
            for(int dc = 0; dc < 4; dc++)
                s = __builtin_amdgcn_mfma_f32_32x32x16_f16(ak[dc], aq[dc], s, 0, 0, 0);
            // S^T layout: lane's 16 values belong to qrow = qrow0+l31; kcol_local = (r&3)+8*(r>>2)+4*hi.
            // Process in two halves h: pf[0..7] covers kcols of A-chunk kc=h exactly.
            #pragma unroll
            for(int h = 0; h < 2; h++){
                float pf[8], ls = 0.f;
                #pragma unroll
                for(int r = 0; r < 8; r++){
                    float p = __builtin_amdgcn_exp2f(fminf(s[h * 8 + r], 15.f));
                    pf[r] = p; ls += p;
                }
                lp += ls;
                unsigned x0 = __builtin_bit_cast(unsigned, __builtin_amdgcn_cvt_pkrtz(pf[0], pf[1]));
                unsigned x1 = __builtin_bit_cast(unsigned, __builtin_amdgcn_cvt_pkrtz(pf[2], pf[3]));
                unsigned y0 = __builtin_bit_cast(unsigned, __builtin_amdgcn_cvt_pkrtz(pf[4], pf[5]));
                unsigned y1 = __builtin_bit_cast(unsigned, __builtin_amdgcn_cvt_pkrtz(pf[6], pf[7]));
                asm("v_permlane32_swap_b32 %0, %1" : "+v"(x0), "+v"(y0));
                asm("v_permlane32_swap_b32 %0, %1" : "+v"(x1), "+v"(y1));
                u32x4 pw = {x0, x1, y0, y1};
                half8 pa = __builtin_bit_cast(half8, pw);
                // V fragments for chunk h: lane holds d = dt*32+l31, kcols kt*32 + h*16 + hi*8
                #pragma unroll
                for(int dt = 0; dt < 2; dt++){
                    half8 vb = *(const half8*)&Vb[(dt * 32 + l31) * LDW + kt * 32 + h * 16 + hi * 8];
                    o[dt] = __builtin_amdgcn_mfma_f32_32x32x16_f16(pa, vb, o[dt], 0, 0, 0);
                }
            }
        }
        if(j < 7){
            f16* wb = &KV[0][0] + (cur ^ 1) * BUF;
            #pragma unroll
            for(int i = 0; i < 4; i++) *(half8*)(wb + loff[i]) = pre[i];
        }
        cur ^= 1;
        __syncthreads();
    }
    // row sums: lanes l and l+32 hold the same qrow
    {
        float v = lp + __shfl_xor(lp, 32);
        if(hi == 0){
            int row = qrow0 + l31;
            lw[kq * 16384 + row] = v;
            lred[w][l31] = __builtin_amdgcn_rcpf(v);
        }
    }
    // O layout: lane holds d = dt*32+l31; qrow = (r&3)+8*(r>>2)+4*hi
    #pragma unroll
    for(int r = 0; r < 16; r++){
        int qrl = (r & 3) + 8 * (r >> 2) + 4 * hi;
        float inv = lred[w][qrl];
        int row = qrow0 + qrl;
        #pragma unroll
        for(int dt = 0; dt < 2; dt++)
            Oph[kq * 1048576 + row * 64 + dt * 32 + l31] = (f16)(o[dt][r] * inv);
    }
}

// ---------------- K4: weighted merge of normalized partials, W4 projection + bias + residual (r4 verbatim) ----
__global__ __launch_bounds__(256) void k_merge(
    const f16* __restrict__ Oph, const float* __restrict__ lw,
    const float* __restrict__ w4, const float* __restrict__ b4,
    const float* __restrict__ x, float* __restrict__ out){
    __shared__ f16 Om[64 * LDW];
    __shared__ f16 wT[64 * LDW];
    __shared__ float b4f[64];
    int t = threadIdx.x;
    int rb = blockIdx.x * 64;
    for(int i = t; i < 4096; i += 256){
        int k = i >> 6, n = i & 63;
        wT[n * LDW + k] = (f16)w4[i];
    }
    if(t < 64) b4f[t] = b4[t];
    for(int i = t; i < 512; i += 256){
        int row = i >> 3, c8 = i & 7;
        int gr = rb + row;
        float num[8] = {0.f,0.f,0.f,0.f,0.f,0.f,0.f,0.f};
        float den = 0.f;
        #pragma unroll
        for(int s = 0; s < 8; s++){
            float li = lw[s * 16384 + gr];
            half8 ov = *(const half8*)&Oph[s * 1048576 + gr * 64 + c8 * 8];
            #pragma unroll
            for(int j = 0; j < 8; j++) num[j] += li * (float)ov[j];
            den += li;
        }
        float invd = 1.f / den;
        #pragma unroll
        for(int j = 0; j < 8; j++) Om[row * LDW + c8 * 8 + j] = (f16)(num[j] * invd);
    }
    __syncthreads();
    int w = t >> 6, lane = t & 63, quad = lane >> 4, l15 = lane & 15;
    half8 a[2];
    #pragma unroll
    for(int kc = 0; kc < 2; kc++)
        a[kc] = *(half8*)&Om[(w * 16 + l15) * LDW + kc * 32 + quad * 8];
    #pragma unroll
    for(int nt = 0; nt < 4; nt++){
        f32x4 y = {0.f, 0.f, 0.f, 0.f};
        #pragma unroll
        for(int kc = 0; kc < 2; kc++){
            half8 bfr = *(half8*)&wT[(nt * 16 + l15) * LDW + kc * 32 + quad * 8];
            y = __builtin_amdgcn_mfma_f32_16x16x32_f16(a[kc], bfr, y, 0, 0, 0);
        }
        #pragma unroll
        for(int r = 0; r < 4; r++){
            int row = rb + w * 16 + quad * 4 + r;
            int col = nt * 16 + l15;
            out[row * 64 + col] = y[r] + b4f[col] + x[row * 64 + col];
        }
    }
}

extern "C" void kernel_launch(void* const* d_in, const int* in_sizes, int n_in,
                              void* d_out, int out_size, void* d_ws, size_t ws_size,
                              hipStream_t stream){
    (void)in_sizes; (void)n_in; (void)out_size; (void)ws_size;
    const float* x  = (const float*)d_in[0];
    const float* w1 = (const float*)d_in[1];
    const float* w2 = (const float*)d_in[2];
    const float* w3 = (const float*)d_in[3];
    const float* w4 = (const float*)d_in[4];
    const float* b1 = (const float*)d_in[5];
    const float* b2 = (const float*)d_in[6];
    const float* b3 = (const float*)d_in[7];
    const float* b4 = (const float*)d_in[8];
    const float* gm = (const float*)d_in[9];
    const float* bt = (const float*)d_in[10];
    char* ws = (char*)d_ws;
    f16* Q    = (f16*)(ws);
    f16* Kx   = (f16*)(ws + (size_t)(2u << 20));
    f16* Vt   = (f16*)(ws + (size_t)(4u << 20));
    float* part = (float*)(ws + (size_t)(6u << 20));                         // 256 x 128 f32 = 128KB
    f16* Oph  = (f16*)(ws + (size_t)(8u << 20));                             // 8 x 2MB (f16, normalized)
    float* lwp = (float*)(ws + (size_t)(24u << 20));                         // 8 x 64KB

    hipLaunchKernelGGL(k_bnstats, dim3(256),  dim3(256), 0, stream, x, part);
    hipLaunchKernelGGL(k_qkv,     dim3(256),  dim3(256), 0, stream, x, w1, w2, w3, b1, b2, b3, gm, bt, part, Q, Kx, Vt);
    hipLaunchKernelGGL(k_attn,    dim3(1024), dim3(256), 0, stream, Q, Kx, Vt, Oph, lwp);
    hipLaunchKernelGGL(k_merge,   dim3(256),  dim3(256), 0, stream, Oph, lwp, w4, b4, x, (float*)d_out);
}

// Round 12
// 127.705 us; speedup vs baseline: 1.2973x; 1.0080x over previous
//
#include <hip/hip_runtime.h>

typedef _Float16 f16;
typedef _Float16 half8 __attribute__((ext_vector_type(8)));
typedef float f32x4 __attribute__((ext_vector_type(4)));
typedef float f32x16 __attribute__((ext_vector_type(16)));
typedef unsigned u32x4 __attribute__((ext_vector_type(4)));

#define LDW 72  // padded LDS leading dim (f16): 144B row stride

// ---------------- K1: BatchNorm statistics -> per-block partials (r4 verbatim) ----------------
__global__ __launch_bounds__(256) void k_bnstats(const float* __restrict__ x, float* __restrict__ part){
    __shared__ float red[512];
    int t = threadIdx.x;
    int c = t & 63, rg = t >> 6;
    int rb = blockIdx.x * 64;
    float s = 0.f, s2 = 0.f;
    for(int r = rg; r < 64; r += 4){
        float v = x[(rb + r) * 64 + c];
        s += v; s2 += v * v;
    }
    red[t] = s; red[256 + t] = s2;
    __syncthreads();
    if(t < 128){
        int c2 = t & 63, h = t >> 6;
        float a = red[h * 256 + c2] + red[h * 256 + c2 + 64] + red[h * 256 + c2 + 128] + red[h * 256 + c2 + 192];
        part[blockIdx.x * 128 + t] = a;
    }
}

// ---------------- K2: partial-reduce + BN apply + QKV projections (r4 verbatim) ----------------
__global__ __launch_bounds__(256) void k_qkv(
    const float* __restrict__ x,
    const float* __restrict__ w1, const float* __restrict__ w2, const float* __restrict__ w3,
    const float* __restrict__ b1, const float* __restrict__ b2, const float* __restrict__ b3,
    const float* __restrict__ gamma, const float* __restrict__ beta,
    const float* __restrict__ part,
    f16* __restrict__ Q, f16* __restrict__ Kx, f16* __restrict__ Vt){
    __shared__ f16 wT[3 * 64 * LDW];
    __shared__ float sc[64], sh[64], bb[3][64];
    __shared__ float psum[128];
    int t = threadIdx.x;
    for(int i = t; i < 3 * 4096; i += 256){
        int j = i >> 12, e = i & 4095, k = e >> 6, n = e & 63;
        const float* wp = (j == 0) ? w1 : ((j == 1) ? w2 : w3);
        wT[j * 64 * LDW + n * LDW + k] = (f16)wp[e];
    }
    if(t < 128){
        float a0 = 0.f, a1 = 0.f, a2 = 0.f, a3 = 0.f;
        for(int b = 0; b < 256; b += 4){
            a0 += part[b * 128 + t];       a1 += part[(b + 1) * 128 + t];
            a2 += part[(b + 2) * 128 + t]; a3 += part[(b + 3) * 128 + t];
        }
        psum[t] = (a0 + a1) + (a2 + a3);
    }
    __syncthreads();
    if(t < 64){
        float mean = psum[t] * (1.f / 16384.f);
        float var  = psum[64 + t] * (1.f / 16384.f) - mean * mean;
        float s = gamma[t] * rsqrtf(var + 1e-5f);
        sc[t] = s;
        sh[t] = beta[t] - mean * s;
        bb[0][t] = b1[t]; bb[1][t] = b2[t]; bb[2][t] = b3[t];
    }
    __syncthreads();
    int w = t >> 6, lane = t & 63, quad = lane >> 4, l15 = lane & 15;
    int rowb = blockIdx.x * 64 + w * 16;
    int arow = rowb + l15;
    half8 a[2];
    #pragma unroll
    for(int kc = 0; kc < 2; kc++){
        f32x4 x0 = *(const f32x4*)&x[arow * 64 + kc * 32 + quad * 8];
        f32x4 x1 = *(const f32x4*)&x[arow * 64 + kc * 32 + quad * 8 + 4];
        half8 h;
        #pragma unroll
        for(int j = 0; j < 8; j++){
            int c = kc * 32 + quad * 8 + j;
            float xv = (j < 4) ? x0[j & 3] : x1[j & 3];
            h[j] = (f16)(xv * sc[c] + sh[c]);
        }
        a[kc] = h;
    }
    const f32x4 vzero = {0.f, 0.f, 0.f, 0.f};
    f32x4 acc[3][4];
    #pragma unroll
    for(int m = 0; m < 3; m++){
        #pragma unroll
        for(int nt = 0; nt < 4; nt++){
            acc[m][nt] = vzero;
            #pragma unroll
            for(int kc = 0; kc < 2; kc++){
                half8 bfr = *(half8*)&wT[m * 64 * LDW + (nt * 16 + l15) * LDW + kc * 32 + quad * 8];
                acc[m][nt] = __builtin_amdgcn_mfma_f32_16x16x32_f16(a[kc], bfr, acc[m][nt], 0, 0, 0);
            }
        }
    }
    const float qs = 0.18033688011112043f;  // log2(e)/8
    #pragma unroll
    for(int nt = 0; nt < 4; nt++){
        #pragma unroll
        for(int r = 0; r < 4; r++){
            int row = rowb + quad * 4 + r;
            int col = nt * 16 + l15;
            Q[row * 64 + col]  = (f16)((acc[0][nt][r] + bb[0][col]) * qs);
            Kx[row * 64 + col] = (f16)(acc[1][nt][r] + bb[1][col]);
            Vt[((row >> 12) * 64 + col) * 4096 + (row & 4095)] = (f16)(acc[2][nt][r] + bb[2][col]);
        }
    }
}

// ---------------- K3: streaming attention, split-K=4 (16 tiles/block), spill-free ----------------
// grid 512 = exactly 2 blocks/CU x 256 CU (single residency wave, no scheduling tail).
// kq = bid&3 (K-quarter), qg = bid>>2 (128-row Q groups). 32 Q-rows/wave; swapped-QK^T 32x32x16;
// in-register softmax in TWO 8-element halves (halved live range, no spill at 128-VGPR cap).
// 1-deep register prefetch staging. Partials NORMALIZED (o/l) f16 + l f32 (4 slices).
__global__ __launch_bounds__(256, 2) void k_attn(
    const f16* __restrict__ Q, const f16* __restrict__ Kx, const f16* __restrict__ Vt,
    f16* __restrict__ Oph, float* __restrict__ lw){
    __shared__ f16 KV[2][2 * 64 * LDW];
    __shared__ float lred[4][32];
    int t = threadIdx.x;
    int kq = blockIdx.x & 3, qg = blockIdx.x >> 2;   // qg in [0,128)
    int b = qg >> 5;
    int w = t >> 6, lane = t & 63, l31 = lane & 31, hi = lane >> 5;
    int qrow0 = qg * 128 + w * 32;
    const int BUF = 2 * 64 * LDW;

    // Q fragments (B-operand): lane holds qrow = qrow0+l31, d-elems dc*16 + hi*8 .. +7
    half8 aq[4];
    #pragma unroll
    for(int dc = 0; dc < 4; dc++)
        aq[dc] = *(const half8*)&Q[(qrow0 + l31) * 64 + dc * 16 + hi * 8];

    // staging: 1024 x 16B chunks per 64-row tile (512 K + 512 V^T); 4 chunks/thread.
    // i=0,1 -> K chunks (step 4096); i=2,3 -> V^T chunks (step 64).
    const f16* gsrc[4];
    int loff[4];
    #pragma unroll
    for(int i = 0; i < 4; i++){
        int idx = t + i * 256;
        int rr = (idx >> 3) & 63, c8 = idx & 7;
        if(i < 2){
            loff[i] = rr * LDW + c8 * 8;
            gsrc[i] = &Kx[(b * 4096 + kq * 1024 + rr) * 64 + c8 * 8];
        } else {
            loff[i] = 64 * LDW + rr * LDW + c8 * 8;
            gsrc[i] = &Vt[(b * 64 + rr) * 4096 + kq * 1024 + c8 * 8];
        }
    }
    half8 pre[4];
    #pragma unroll
    for(int i = 0; i < 4; i++){ pre[i] = *(const half8*)gsrc[i]; gsrc[i] += (i < 2) ? 4096 : 64; }
    #pragma unroll
    for(int i = 0; i < 4; i++) *(half8*)&KV[0][loff[i]] = pre[i];

    f32x16 o[2];
    #pragma unroll
    for(int dt = 0; dt < 2; dt++)
        #pragma unroll
        for(int r = 0; r < 16; r++) o[dt][r] = 0.f;
    float lp = 0.f;

    __syncthreads();
    int cur = 0;
    for(int j = 0; j < 16; j++){
        if(j < 15){  // issue next-tile global loads early; consumed at tile end (T14)
            #pragma unroll
            for(int i = 0; i < 4; i++){ pre[i] = *(const half8*)gsrc[i]; gsrc[i] += (i < 2) ? 4096 : 64; }
        }
        const f16* Kb = &KV[0][0] + cur * BUF;
        const f16* Vb = Kb + 64 * LDW;
        #pragma unroll
        for(int kt = 0; kt < 2; kt++){
            // K fragments (A-operand): lane holds kcol = kt*32+l31, d-elems dc*16 + hi*8
            half8 ak[4];
            #pragma unroll
            for(int dc = 0; dc < 4; dc++)
                ak[dc] = *(const half8*)&Kb[(kt * 32 + l31) * LDW + dc * 16 + hi * 8];
            f32x16 s;
            #pragma unroll
            for(int r = 0; r < 16; r++) s[r] = 0.f;
            #pragma unroll
            for(int dc = 0; dc < 4; dc++)
                s = __builtin_amdgcn_mfma_f32_32x32x16_f16(ak[dc], aq[dc], s, 0, 0, 0);
            // S^T layout: lane's 16 values belong to qrow = qrow0+l31; kcol_local = (r&3)+8*(r>>2)+4*hi.
            // Two halves h: pf[0..7] covers kcols of A-chunk kc=h exactly.
            #pragma unroll
            for(int h = 0; h < 2; h++){
                float pf[8], ls = 0.f;
                #pragma unroll
                for(int r = 0; r < 8; r++){
                    float p = __builtin_amdgcn_exp2f(fminf(s[h * 8 + r], 15.f));
                    pf[r] = p; ls += p;
                }
                lp += ls;
                unsigned x0 = __builtin_bit_cast(unsigned, __builtin_amdgcn_cvt_pkrtz(pf[0], pf[1]));
                unsigned x1 = __builtin_bit_cast(unsigned, __builtin_amdgcn_cvt_pkrtz(pf[2], pf[3]));
                unsigned y0 = __builtin_bit_cast(unsigned, __builtin_amdgcn_cvt_pkrtz(pf[4], pf[5]));
                unsigned y1 = __builtin_bit_cast(unsigned, __builtin_amdgcn_cvt_pkrtz(pf[6], pf[7]));
                asm("v_permlane32_swap_b32 %0, %1" : "+v"(x0), "+v"(y0));
                asm("v_permlane32_swap_b32 %0, %1" : "+v"(x1), "+v"(y1));
                u32x4 pw = {x0, x1, y0, y1};
                half8 pa = __builtin_bit_cast(half8, pw);
                // V fragments for chunk h: lane holds d = dt*32+l31, kcols kt*32 + h*16 + hi*8
                #pragma unroll
                for(int dt = 0; dt < 2; dt++){
                    half8 vb = *(const half8*)&Vb[(dt * 32 + l31) * LDW + kt * 32 + h * 16 + hi * 8];
                    o[dt] = __builtin_amdgcn_mfma_f32_32x32x16_f16(pa, vb, o[dt], 0, 0, 0);
                }
            }
        }
        if(j < 15){
            f16* wb = &KV[0][0] + (cur ^ 1) * BUF;
            #pragma unroll
            for(int i = 0; i < 4; i++) *(half8*)(wb + loff[i]) = pre[i];
        }
        cur ^= 1;
        __syncthreads();
    }
    // row sums: lanes l and l+32 hold the same qrow
    {
        float v = lp + __shfl_xor(lp, 32);
        if(hi == 0){
            int row = qrow0 + l31;
            lw[kq * 16384 + row] = v;
            lred[w][l31] = __builtin_amdgcn_rcpf(v);
        }
    }
    // O layout: lane holds d = dt*32+l31; qrow = (r&3)+8*(r>>2)+4*hi
    #pragma unroll
    for(int r = 0; r < 16; r++){
        int qrl = (r & 3) + 8 * (r >> 2) + 4 * hi;
        float inv = lred[w][qrl];
        int row = qrow0 + qrl;
        #pragma unroll
        for(int dt = 0; dt < 2; dt++)
            Oph[kq * 1048576 + row * 64 + dt * 32 + l31] = (f16)(o[dt][r] * inv);
    }
}

// ---------------- K4: weighted merge of 4 normalized partials, W4 projection + bias + residual ----------------
__global__ __launch_bounds__(256) void k_merge(
    const f16* __restrict__ Oph, const float* __restrict__ lw,
    const float* __restrict__ w4, const float* __restrict__ b4,
    const float* __restrict__ x, float* __restrict__ out){
    __shared__ f16 Om[64 * LDW];
    __shared__ f16 wT[64 * LDW];
    __shared__ float b4f[64];
    int t = threadIdx.x;
    int rb = blockIdx.x * 64;
    for(int i = t; i < 4096; i += 256){
        int k = i >> 6, n = i & 63;
        wT[n * LDW + k] = (f16)w4[i];
    }
    if(t < 64) b4f[t] = b4[t];
    for(int i = t; i < 512; i += 256){
        int row = i >> 3, c8 = i & 7;
        int gr = rb + row;
        float num[8] = {0.f,0.f,0.f,0.f,0.f,0.f,0.f,0.f};
        float den = 0.f;
        #pragma unroll
        for(int s = 0; s < 4; s++){
            float li = lw[s * 16384 + gr];
            half8 ov = *(const half8*)&Oph[s * 1048576 + gr * 64 + c8 * 8];
            #pragma unroll
            for(int j = 0; j < 8; j++) num[j] += li * (float)ov[j];
            den += li;
        }
        float invd = 1.f / den;
        #pragma unroll
        for(int j = 0; j < 8; j++) Om[row * LDW + c8 * 8 + j] = (f16)(num[j] * invd);
    }
    __syncthreads();
    int w = t >> 6, lane = t & 63, quad = lane >> 4, l15 = lane & 15;
    half8 a[2];
    #pragma unroll
    for(int kc = 0; kc < 2; kc++)
        a[kc] = *(half8*)&Om[(w * 16 + l15) * LDW + kc * 32 + quad * 8];
    #pragma unroll
    for(int nt = 0; nt < 4; nt++){
        f32x4 y = {0.f, 0.f, 0.f, 0.f};
        #pragma unroll
        for(int kc = 0; kc < 2; kc++){
            half8 bfr = *(half8*)&wT[(nt * 16 + l15) * LDW + kc * 32 + quad * 8];
            y = __builtin_amdgcn_mfma_f32_16x16x32_f16(a[kc], bfr, y, 0, 0, 0);
        }
        #pragma unroll
        for(int r = 0; r < 4; r++){
            int row = rb + w * 16 + quad * 4 + r;
            int col = nt * 16 + l15;
            out[row * 64 + col] = y[r] + b4f[col] + x[row * 64 + col];
        }
    }
}

extern "C" void kernel_launch(void* const* d_in, const int* in_sizes, int n_in,
                              void* d_out, int out_size, void* d_ws, size_t ws_size,
                              hipStream_t stream){
    (void)in_sizes; (void)n_in; (void)out_size; (void)ws_size;
    const float* x  = (const float*)d_in[0];
    const float* w1 = (const float*)d_in[1];
    const float* w2 = (const float*)d_in[2];
    const float* w3 = (const float*)d_in[3];
    const float* w4 = (const float*)d_in[4];
    const float* b1 = (const float*)d_in[5];
    const float* b2 = (const float*)d_in[6];
    const float* b3 = (const float*)d_in[7];
    const float* b4 = (const float*)d_in[8];
    const float* gm = (const float*)d_in[9];
    const float* bt = (const float*)d_in[10];
    char* ws = (char*)d_ws;
    f16* Q    = (f16*)(ws);
    f16* Kx   = (f16*)(ws + (size_t)(2u << 20));
    f16* Vt   = (f16*)(ws + (size_t)(4u << 20));
    float* part = (float*)(ws + (size_t)(6u << 20));                         // 256 x 128 f32 = 128KB
    f16* Oph  = (f16*)(ws + (size_t)(8u << 20));                             // 4 x 2MB (f16, normalized)
    float* lwp = (float*)(ws + (size_t)(24u << 20));                         // 4 x 64KB

    hipLaunchKernelGGL(k_bnstats, dim3(256), dim3(256), 0, stream, x, part);
    hipLaunchKernelGGL(k_qkv,     dim3(256), dim3(256), 0, stream, x, w1, w2, w3, b1, b2, b3, gm, bt, part, Q, Kx, Vt);
    hipLaunchKernelGGL(k_attn,    dim3(512), dim3(256), 0, stream, Q, Kx, Vt, Oph, lwp);
    hipLaunchKernelGGL(k_merge,   dim3(256), dim3(256), 0, stream, Oph, lwp, w4, b4, x, (float*)d_out);
}

// Round 13
// 125.944 us; speedup vs baseline: 1.3154x; 1.0140x over previous
//
#include <hip/hip_runtime.h>

typedef _Float16 f16;
typedef _Float16 half8 __attribute__((ext_vector_type(8)));
typedef float f32x4 __attribute__((ext_vector_type(4)));
typedef float f32x16 __attribute__((ext_vector_type(16)));
typedef unsigned u32x4 __attribute__((ext_vector_type(4)));

#define LDW 72  // padded LDS leading dim (f16): 144B row stride

// ---------------- K1: BatchNorm statistics -> per-block partials (r4 verbatim) ----------------
__global__ __launch_bounds__(256) void k_bnstats(const float* __restrict__ x, float* __restrict__ part){
    __shared__ float red[512];
    int t = threadIdx.x;
    int c = t & 63, rg = t >> 6;
    int rb = blockIdx.x * 64;
    float s = 0.f, s2 = 0.f;
    for(int r = rg; r < 64; r += 4){
        float v = x[(rb + r) * 64 + c];
        s += v; s2 += v * v;
    }
    red[t] = s; red[256 + t] = s2;
    __syncthreads();
    if(t < 128){
        int c2 = t & 63, h = t >> 6;
        float a = red[h * 256 + c2] + red[h * 256 + c2 + 64] + red[h * 256 + c2 + 128] + red[h * 256 + c2 + 192];
        part[blockIdx.x * 128 + t] = a;
    }
}

// ---------------- K2: partial-reduce + BN apply + QKV projections (r4 verbatim) ----------------
__global__ __launch_bounds__(256) void k_qkv(
    const float* __restrict__ x,
    const float* __restrict__ w1, const float* __restrict__ w2, const float* __restrict__ w3,
    const float* __restrict__ b1, const float* __restrict__ b2, const float* __restrict__ b3,
    const float* __restrict__ gamma, const float* __restrict__ beta,
    const float* __restrict__ part,
    f16* __restrict__ Q, f16* __restrict__ Kx, f16* __restrict__ Vt){
    __shared__ f16 wT[3 * 64 * LDW];
    __shared__ float sc[64], sh[64], bb[3][64];
    __shared__ float psum[128];
    int t = threadIdx.x;
    for(int i = t; i < 3 * 4096; i += 256){
        int j = i >> 12, e = i & 4095, k = e >> 6, n = e & 63;
        const float* wp = (j == 0) ? w1 : ((j == 1) ? w2 : w3);
        wT[j * 64 * LDW + n * LDW + k] = (f16)wp[e];
    }
    if(t < 128){
        float a0 = 0.f, a1 = 0.f, a2 = 0.f, a3 = 0.f;
        for(int b = 0; b < 256; b += 4){
            a0 += part[b * 128 + t];       a1 += part[(b + 1) * 128 + t];
            a2 += part[(b + 2) * 128 + t]; a3 += part[(b + 3) * 128 + t];
        }
        psum[t] = (a0 + a1) + (a2 + a3);
    }
    __syncthreads();
    if(t < 64){
        float mean = psum[t] * (1.f / 16384.f);
        float var  = psum[64 + t] * (1.f / 16384.f) - mean * mean;
        float s = gamma[t] * rsqrtf(var + 1e-5f);
        sc[t] = s;
        sh[t] = beta[t] - mean * s;
        bb[0][t] = b1[t]; bb[1][t] = b2[t]; bb[2][t] = b3[t];
    }
    __syncthreads();
    int w = t >> 6, lane = t & 63, quad = lane >> 4, l15 = lane & 15;
    int rowb = blockIdx.x * 64 + w * 16;
    int arow = rowb + l15;
    half8 a[2];
    #pragma unroll
    for(int kc = 0; kc < 2; kc++){
        f32x4 x0 = *(const f32x4*)&x[arow * 64 + kc * 32 + quad * 8];
        f32x4 x1 = *(const f32x4*)&x[arow * 64 + kc * 32 + quad * 8 + 4];
        half8 h;
        #pragma unroll
        for(int j = 0; j < 8; j++){
            int c = kc * 32 + quad * 8 + j;
            float xv = (j < 4) ? x0[j & 3] : x1[j & 3];
            h[j] = (f16)(xv * sc[c] + sh[c]);
        }
        a[kc] = h;
    }
    const f32x4 vzero = {0.f, 0.f, 0.f, 0.f};
    f32x4 acc[3][4];
    #pragma unroll
    for(int m = 0; m < 3; m++){
        #pragma unroll
        for(int nt = 0; nt < 4; nt++){
            acc[m][nt] = vzero;
            #pragma unroll
            for(int kc = 0; kc < 2; kc++){
                half8 bfr = *(half8*)&wT[m * 64 * LDW + (nt * 16 + l15) * LDW + kc * 32 + quad * 8];
                acc[m][nt] = __builtin_amdgcn_mfma_f32_16x16x32_f16(a[kc], bfr, acc[m][nt], 0, 0, 0);
            }
        }
    }
    const float qs = 0.18033688011112043f;  // log2(e)/8
    #pragma unroll
    for(int nt = 0; nt < 4; nt++){
        #pragma unroll
        for(int r = 0; r < 4; r++){
            int row = rowb + quad * 4 + r;
            int col = nt * 16 + l15;
            Q[row * 64 + col]  = (f16)((acc[0][nt][r] + bb[0][col]) * qs);
            Kx[row * 64 + col] = (f16)(acc[1][nt][r] + bb[1][col]);
            Vt[((row >> 12) * 64 + col) * 4096 + (row & 4095)] = (f16)(acc[2][nt][r] + bb[2][col]);
        }
    }
}

// ---------------- K3: streaming attention, split-K=4, spill-free, setprio around MFMA (T5) ----------------
// grid 512 = exactly 2 blocks/CU x 256 CU (single residency wave). kq = bid&3, qg = bid>>2.
// 32 Q-rows/wave; swapped-QK^T 32x32x16; in-register softmax in TWO 8-element halves.
// 1-deep register prefetch staging. Partials NORMALIZED (o/l) f16 + l f32 (4 slices).
__global__ __launch_bounds__(256, 2) void k_attn(
    const f16* __restrict__ Q, const f16* __restrict__ Kx, const f16* __restrict__ Vt,
    f16* __restrict__ Oph, float* __restrict__ lw){
    __shared__ f16 KV[2][2 * 64 * LDW];
    __shared__ float lred[4][32];
    int t = threadIdx.x;
    int kq = blockIdx.x & 3, qg = blockIdx.x >> 2;   // qg in [0,128)
    int b = qg >> 5;
    int w = t >> 6, lane = t & 63, l31 = lane & 31, hi = lane >> 5;
    int qrow0 = qg * 128 + w * 32;
    const int BUF = 2 * 64 * LDW;

    // Q fragments (B-operand): lane holds qrow = qrow0+l31, d-elems dc*16 + hi*8 .. +7
    half8 aq[4];
    #pragma unroll
    for(int dc = 0; dc < 4; dc++)
        aq[dc] = *(const half8*)&Q[(qrow0 + l31) * 64 + dc * 16 + hi * 8];

    // staging: 1024 x 16B chunks per 64-row tile (512 K + 512 V^T); 4 chunks/thread.
    const f16* gsrc[4];
    int loff[4];
    #pragma unroll
    for(int i = 0; i < 4; i++){
        int idx = t + i * 256;
        int rr = (idx >> 3) & 63, c8 = idx & 7;
        if(i < 2){
            loff[i] = rr * LDW + c8 * 8;
            gsrc[i] = &Kx[(b * 4096 + kq * 1024 + rr) * 64 + c8 * 8];
        } else {
            loff[i] = 64 * LDW + rr * LDW + c8 * 8;
            gsrc[i] = &Vt[(b * 64 + rr) * 4096 + kq * 1024 + c8 * 8];
        }
    }
    half8 pre[4];
    #pragma unroll
    for(int i = 0; i < 4; i++){ pre[i] = *(const half8*)gsrc[i]; gsrc[i] += (i < 2) ? 4096 : 64; }
    #pragma unroll
    for(int i = 0; i < 4; i++) *(half8*)&KV[0][loff[i]] = pre[i];

    f32x16 o[2];
    #pragma unroll
    for(int dt = 0; dt < 2; dt++)
        #pragma unroll
        for(int r = 0; r < 16; r++) o[dt][r] = 0.f;
    float lp = 0.f;

    __syncthreads();
    int cur = 0;
    for(int j = 0; j < 16; j++){
        if(j < 15){  // issue next-tile global loads early; consumed at tile end (T14)
            #pragma unroll
            for(int i = 0; i < 4; i++){ pre[i] = *(const half8*)gsrc[i]; gsrc[i] += (i < 2) ? 4096 : 64; }
        }
        const f16* Kb = &KV[0][0] + cur * BUF;
        const f16* Vb = Kb + 64 * LDW;
        #pragma unroll
        for(int kt = 0; kt < 2; kt++){
            // K fragments (A-operand): lane holds kcol = kt*32+l31, d-elems dc*16 + hi*8
            half8 ak[4];
            #pragma unroll
            for(int dc = 0; dc < 4; dc++)
                ak[dc] = *(const half8*)&Kb[(kt * 32 + l31) * LDW + dc * 16 + hi * 8];
            __builtin_amdgcn_s_setprio(1);
            f32x16 s;
            #pragma unroll
            for(int r = 0; r < 16; r++) s[r] = 0.f;
            #pragma unroll
            for(int dc = 0; dc < 4; dc++)
                s = __builtin_amdgcn_mfma_f32_32x32x16_f16(ak[dc], aq[dc], s, 0, 0, 0);
            __builtin_amdgcn_s_setprio(0);
            // S^T layout: lane's 16 values belong to qrow = qrow0+l31; kcol_local = (r&3)+8*(r>>2)+4*hi.
            // Two halves h: pf[0..7] covers kcols of A-chunk kc=h exactly.
            #pragma unroll
            for(int h = 0; h < 2; h++){
                float pf[8], ls = 0.f;
                #pragma unroll
                for(int r = 0; r < 8; r++){
                    float p = __builtin_amdgcn_exp2f(fminf(s[h * 8 + r], 15.f));
                    pf[r] = p; ls += p;
                }
                lp += ls;
                unsigned x0 = __builtin_bit_cast(unsigned, __builtin_amdgcn_cvt_pkrtz(pf[0], pf[1]));
                unsigned x1 = __builtin_bit_cast(unsigned, __builtin_amdgcn_cvt_pkrtz(pf[2], pf[3]));
                unsigned y0 = __builtin_bit_cast(unsigned, __builtin_amdgcn_cvt_pkrtz(pf[4], pf[5]));
                unsigned y1 = __builtin_bit_cast(unsigned, __builtin_amdgcn_cvt_pkrtz(pf[6], pf[7]));
                asm("v_permlane32_swap_b32 %0, %1" : "+v"(x0), "+v"(y0));
                asm("v_permlane32_swap_b32 %0, %1" : "+v"(x1), "+v"(y1));
                u32x4 pw = {x0, x1, y0, y1};
                half8 pa = __builtin_bit_cast(half8, pw);
                // V fragments for chunk h: lane holds d = dt*32+l31, kcols kt*32 + h*16 + hi*8
                __builtin_amdgcn_s_setprio(1);
                #pragma unroll
                for(int dt = 0; dt < 2; dt++){
                    half8 vb = *(const half8*)&Vb[(dt * 32 + l31) * LDW + kt * 32 + h * 16 + hi * 8];
                    o[dt] = __builtin_amdgcn_mfma_f32_32x32x16_f16(pa, vb, o[dt], 0, 0, 0);
                }
                __builtin_amdgcn_s_setprio(0);
            }
        }
        if(j < 15){
            f16* wb = &KV[0][0] + (cur ^ 1) * BUF;
            #pragma unroll
            for(int i = 0; i < 4; i++) *(half8*)(wb + loff[i]) = pre[i];
        }
        cur ^= 1;
        __syncthreads();
    }
    // row sums: lanes l and l+32 hold the same qrow
    {
        float v = lp + __shfl_xor(lp, 32);
        if(hi == 0){
            int row = qrow0 + l31;
            lw[kq * 16384 + row] = v;
            lred[w][l31] = __builtin_amdgcn_rcpf(v);
        }
    }
    // O layout: lane holds d = dt*32+l31; qrow = (r&3)+8*(r>>2)+4*hi
    #pragma unroll
    for(int r = 0; r < 16; r++){
        int qrl = (r & 3) + 8 * (r >> 2) + 4 * hi;
        float inv = lred[w][qrl];
        int row = qrow0 + qrl;
        #pragma unroll
        for(int dt = 0; dt < 2; dt++)
            Oph[kq * 1048576 + row * 64 + dt * 32 + l31] = (f16)(o[dt][r] * inv);
    }
}

// ---------------- K4: weighted merge of 4 normalized partials, W4 projection + bias + residual ----------------
__global__ __launch_bounds__(256) void k_merge(
    const f16* __restrict__ Oph, const float* __restrict__ lw,
    const float* __restrict__ w4, const float* __restrict__ b4,
    const float* __restrict__ x, float* __restrict__ out){
    __shared__ f16 Om[64 * LDW];
    __shared__ f16 wT[64 * LDW];
    __shared__ float b4f[64];
    int t = threadIdx.x;
    int rb = blockIdx.x * 64;
    for(int i = t; i < 4096; i += 256){
        int k = i >> 6, n = i & 63;
        wT[n * LDW + k] = (f16)w4[i];
    }
    if(t < 64) b4f[t] = b4[t];
    for(int i = t; i < 512; i += 256){
        int row = i >> 3, c8 = i & 7;
        int gr = rb + row;
        float num[8] = {0.f,0.f,0.f,0.f,0.f,0.f,0.f,0.f};
        float den = 0.f;
        #pragma unroll
        for(int s = 0; s < 4; s++){
            float li = lw[s * 16384 + gr];
            half8 ov = *(const half8*)&Oph[s * 1048576 + gr * 64 + c8 * 8];
            #pragma unroll
            for(int j = 0; j < 8; j++) num[j] += li * (float)ov[j];
            den += li;
        }
        float invd = 1.f / den;
        #pragma unroll
        for(int j = 0; j < 8; j++) Om[row * LDW + c8 * 8 + j] = (f16)(num[j] * invd);
    }
    __syncthreads();
    int w = t >> 6, lane = t & 63, quad = lane >> 4, l15 = lane & 15;
    half8 a[2];
    #pragma unroll
    for(int kc = 0; kc < 2; kc++)
        a[kc] = *(half8*)&Om[(w * 16 + l15) * LDW + kc * 32 + quad * 8];
    #pragma unroll
    for(int nt = 0; nt < 4; nt++){
        f32x4 y = {0.f, 0.f, 0.f, 0.f};
        #pragma unroll
        for(int kc = 0; kc < 2; kc++){
            half8 bfr = *(half8*)&wT[(nt * 16 + l15) * LDW + kc * 32 + quad * 8];
            y = __builtin_amdgcn_mfma_f32_16x16x32_f16(a[kc], bfr, y, 0, 0, 0);
        }
        #pragma unroll
        for(int r = 0; r < 4; r++){
            int row = rb + w * 16 + quad * 4 + r;
            int col = nt * 16 + l15;
            out[row * 64 + col] = y[r] + b4f[col] + x[row * 64 + col];
        }
    }
}

extern "C" void kernel_launch(void* const* d_in, const int* in_sizes, int n_in,
                              void* d_out, int out_size, void* d_ws, size_t ws_size,
                              hipStream_t stream){
    (void)in_sizes; (void)n_in; (void)out_size; (void)ws_size;
    const float* x  = (const float*)d_in[0];
    const float* w1 = (const float*)d_in[1];
    const float* w2 = (const float*)d_in[2];
    const float* w3 = (const float*)d_in[3];
    const float* w4 = (const float*)d_in[4];
    const float* b1 = (const float*)d_in[5];
    const float* b2 = (const float*)d_in[6];
    const float* b3 = (const float*)d_in[7];
    const float* b4 = (const float*)d_in[8];
    const float* gm = (const float*)d_in[9];
    const float* bt = (const float*)d_in[10];
    char* ws = (char*)d_ws;
    f16* Q    = (f16*)(ws);
    f16* Kx   = (f16*)(ws + (size_t)(2u << 20));
    f16* Vt   = (f16*)(ws + (size_t)(4u << 20));
    float* part = (float*)(ws + (size_t)(6u << 20));                         // 256 x 128 f32 = 128KB
    f16* Oph  = (f16*)(ws + (size_t)(8u << 20));                             // 4 x 2MB (f16, normalized)
    float* lwp = (float*)(ws + (size_t)(24u << 20));                         // 4 x 64KB

    hipLaunchKernelGGL(k_bnstats, dim3(256), dim3(256), 0, stream, x, part);
    hipLaunchKernelGGL(k_qkv,     dim3(256), dim3(256), 0, stream, x, w1, w2, w3, b1, b2, b3, gm, bt, part, Q, Kx, Vt);
    hipLaunchKernelGGL(k_attn,    dim3(512), dim3(256), 0, stream, Q, Kx, Vt, Oph, lwp);
    hipLaunchKernelGGL(k_merge,   dim3(256), dim3(256), 0, stream, Oph, lwp, w4, b4, x, (float*)d_out);
}

// Round 14
// 124.769 us; speedup vs baseline: 1.3278x; 1.0094x over previous
//
#include <hip/hip_runtime.h>

typedef _Float16 f16;
typedef _Float16 half8 __attribute__((ext_vector_type(8)));
typedef float f32x4 __attribute__((ext_vector_type(4)));
typedef float f32x16 __attribute__((ext_vector_type(16)));
typedef unsigned u32x4 __attribute__((ext_vector_type(4)));

#define LDW 72  // padded LDS leading dim (f16): 144B row stride

// ---------------- K1: BatchNorm statistics -> per-block partials (r4 verbatim) ----------------
__global__ __launch_bounds__(256) void k_bnstats(const float* __restrict__ x, float* __restrict__ part){
    __shared__ float red[512];
    int t = threadIdx.x;
    int c = t & 63, rg = t >> 6;
    int rb = blockIdx.x * 64;
    float s = 0.f, s2 = 0.f;
    for(int r = rg; r < 64; r += 4){
        float v = x[(rb + r) * 64 + c];
        s += v; s2 += v * v;
    }
    red[t] = s; red[256 + t] = s2;
    __syncthreads();
    if(t < 128){
        int c2 = t & 63, h = t >> 6;
        float a = red[h * 256 + c2] + red[h * 256 + c2 + 64] + red[h * 256 + c2 + 128] + red[h * 256 + c2 + 192];
        part[blockIdx.x * 128 + t] = a;
    }
}

// ---------------- K2: partial-reduce + BN apply + QKV projections (r4 verbatim) ----------------
__global__ __launch_bounds__(256) void k_qkv(
    const float* __restrict__ x,
    const float* __restrict__ w1, const float* __restrict__ w2, const float* __restrict__ w3,
    const float* __restrict__ b1, const float* __restrict__ b2, const float* __restrict__ b3,
    const float* __restrict__ gamma, const float* __restrict__ beta,
    const float* __restrict__ part,
    f16* __restrict__ Q, f16* __restrict__ Kx, f16* __restrict__ Vt){
    __shared__ f16 wT[3 * 64 * LDW];
    __shared__ float sc[64], sh[64], bb[3][64];
    __shared__ float psum[128];
    int t = threadIdx.x;
    for(int i = t; i < 3 * 4096; i += 256){
        int j = i >> 12, e = i & 4095, k = e >> 6, n = e & 63;
        const float* wp = (j == 0) ? w1 : ((j == 1) ? w2 : w3);
        wT[j * 64 * LDW + n * LDW + k] = (f16)wp[e];
    }
    if(t < 128){
        float a0 = 0.f, a1 = 0.f, a2 = 0.f, a3 = 0.f;
        for(int b = 0; b < 256; b += 4){
            a0 += part[b * 128 + t];       a1 += part[(b + 1) * 128 + t];
            a2 += part[(b + 2) * 128 + t]; a3 += part[(b + 3) * 128 + t];
        }
        psum[t] = (a0 + a1) + (a2 + a3);
    }
    __syncthreads();
    if(t < 64){
        float mean = psum[t] * (1.f / 16384.f);
        float var  = psum[64 + t] * (1.f / 16384.f) - mean * mean;
        float s = gamma[t] * rsqrtf(var + 1e-5f);
        sc[t] = s;
        sh[t] = beta[t] - mean * s;
        bb[0][t] = b1[t]; bb[1][t] = b2[t]; bb[2][t] = b3[t];
    }
    __syncthreads();
    int w = t >> 6, lane = t & 63, quad = lane >> 4, l15 = lane & 15;
    int rowb = blockIdx.x * 64 + w * 16;
    int arow = rowb + l15;
    half8 a[2];
    #pragma unroll
    for(int kc = 0; kc < 2; kc++){
        f32x4 x0 = *(const f32x4*)&x[arow * 64 + kc * 32 + quad * 8];
        f32x4 x1 = *(const f32x4*)&x[arow * 64 + kc * 32 + quad * 8 + 4];
        half8 h;
        #pragma unroll
        for(int j = 0; j < 8; j++){
            int c = kc * 32 + quad * 8 + j;
            float xv = (j < 4) ? x0[j & 3] : x1[j & 3];
            h[j] = (f16)(xv * sc[c] + sh[c]);
        }
        a[kc] = h;
    }
    const f32x4 vzero = {0.f, 0.f, 0.f, 0.f};
    f32x4 acc[3][4];
    #pragma unroll
    for(int m = 0; m < 3; m++){
        #pragma unroll
        for(int nt = 0; nt < 4; nt++){
            acc[m][nt] = vzero;
            #pragma unroll
            for(int kc = 0; kc < 2; kc++){
                half8 bfr = *(half8*)&wT[m * 64 * LDW + (nt * 16 + l15) * LDW + kc * 32 + quad * 8];
                acc[m][nt] = __builtin_amdgcn_mfma_f32_16x16x32_f16(a[kc], bfr, acc[m][nt], 0, 0, 0);
            }
        }
    }
    const float qs = 0.18033688011112043f;  // log2(e)/8
    #pragma unroll
    for(int nt = 0; nt < 4; nt++){
        #pragma unroll
        for(int r = 0; r < 4; r++){
            int row = rowb + quad * 4 + r;
            int col = nt * 16 + l15;
            Q[row * 64 + col]  = (f16)((acc[0][nt][r] + bb[0][col]) * qs);
            Kx[row * 64 + col] = (f16)(acc[1][nt][r] + bb[1][col]);
            Vt[((row >> 12) * 64 + col) * 4096 + (row & 4095)] = (f16)(acc[2][nt][r] + bb[2][col]);
        }
    }
}

// ---------------- K3: streaming attention, split-K=4, pair-buffered (1 barrier per 2 tiles) ----------------
// grid 512 = exactly 2 blocks/CU x 256 CU. kq = bid&3, qg = bid>>2. 32 Q-rows/wave; swapped-QK^T
// 32x32x16; in-register softmax in TWO 8-element halves; setprio(1) around MFMA clusters (T5).
// LDS: 2 pair-buffers x 2 tile-slots (72KB/block; 148KB/CU at 2 blocks). pre[4] reused twice per
// pair (write slot0's next-tile after slot0 compute, reload, write slot1's after slot1 compute)
// -> barrier count halved (16 -> 8) with unchanged VGPR pressure (the r10 spill lesson).
__global__ __launch_bounds__(256, 2) void k_attn(
    const f16* __restrict__ Q, const f16* __restrict__ Kx, const f16* __restrict__ Vt,
    f16* __restrict__ Oph, float* __restrict__ lw){
    __shared__ f16 KV[2 * 2 * 128 * LDW];            // [buf][slot][K 64xLDW | V^T 64xLDW]
    __shared__ float lred[4][32];
    const int SLOT = 128 * LDW;                      // 9216 f16 per tile-slot
    const int BUF  = 2 * SLOT;                       // per pair-buffer
    int t = threadIdx.x;
    int kq = blockIdx.x & 3, qg = blockIdx.x >> 2;   // qg in [0,128)
    int b = qg >> 5;
    int w = t >> 6, lane = t & 63, l31 = lane & 31, hi = lane >> 5;
    int qrow0 = qg * 128 + w * 32;

    // Q fragments (B-operand): lane holds qrow = qrow0+l31, d-elems dc*16 + hi*8 .. +7
    half8 aq[4];
    #pragma unroll
    for(int dc = 0; dc < 4; dc++)
        aq[dc] = *(const half8*)&Q[(qrow0 + l31) * 64 + dc * 16 + hi * 8];

    // staging: per tile 1024 x 16B chunks (512 K + 512 V^T); 4 chunks/thread.
    // i=0,1 -> K chunks (step 4096 elems/tile); i=2,3 -> V^T chunks (step 64).
    const f16* gsrc[4];
    int loff[4];
    #pragma unroll
    for(int i = 0; i < 4; i++){
        int idx = t + i * 256;
        int rr = (idx >> 3) & 63, c8 = idx & 7;
        if(i < 2){
            loff[i] = rr * LDW + c8 * 8;
            gsrc[i] = &Kx[(b * 4096 + kq * 1024 + rr) * 64 + c8 * 8];
        } else {
            loff[i] = 64 * LDW + rr * LDW + c8 * 8;
            gsrc[i] = &Vt[(b * 64 + rr) * 4096 + kq * 1024 + c8 * 8];
        }
    }
    half8 pre[4];
    // prologue: T0 -> buf0 slot0, T1 -> buf0 slot1, T2 -> pre (in flight)
    #pragma unroll
    for(int i = 0; i < 4; i++){ pre[i] = *(const half8*)gsrc[i]; gsrc[i] += (i < 2) ? 4096 : 64; }
    #pragma unroll
    for(int i = 0; i < 4; i++) *(half8*)&KV[loff[i]] = pre[i];
    #pragma unroll
    for(int i = 0; i < 4; i++){ pre[i] = *(const half8*)gsrc[i]; gsrc[i] += (i < 2) ? 4096 : 64; }
    #pragma unroll
    for(int i = 0; i < 4; i++) *(half8*)&KV[SLOT + loff[i]] = pre[i];
    #pragma unroll
    for(int i = 0; i < 4; i++){ pre[i] = *(const half8*)gsrc[i]; gsrc[i] += (i < 2) ? 4096 : 64; }

    f32x16 o[2];
    #pragma unroll
    for(int dt = 0; dt < 2; dt++)
        #pragma unroll
        for(int r = 0; r < 16; r++) o[dt][r] = 0.f;
    float lp = 0.f;

    __syncthreads();
    int cur = 0;
    for(int jp = 0; jp < 8; jp++){                   // 8 pairs of 64-row kv tiles
        #pragma unroll
        for(int slot = 0; slot < 2; slot++){
            const f16* Kb = &KV[cur * BUF + slot * SLOT];
            const f16* Vb = Kb + 64 * LDW;
            #pragma unroll
            for(int kt = 0; kt < 2; kt++){
                // K fragments (A-operand): lane holds kcol = kt*32+l31, d-elems dc*16 + hi*8
                half8 ak[4];
                #pragma unroll
                for(int dc = 0; dc < 4; dc++)
                    ak[dc] = *(const half8*)&Kb[(kt * 32 + l31) * LDW + dc * 16 + hi * 8];
                __builtin_amdgcn_s_setprio(1);
                f32x16 s;
                #pragma unroll
                for(int r = 0; r < 16; r++) s[r] = 0.f;
                #pragma unroll
                for(int dc = 0; dc < 4; dc++)
                    s = __builtin_amdgcn_mfma_f32_32x32x16_f16(ak[dc], aq[dc], s, 0, 0, 0);
                __builtin_amdgcn_s_setprio(0);
                // S^T layout: lane's 16 values belong to qrow = qrow0+l31;
                // kcol_local = (r&3)+8*(r>>2)+4*hi. Two halves h: pf[0..7] = A-chunk kc=h.
                #pragma unroll
                for(int h = 0; h < 2; h++){
                    float pf[8], ls = 0.f;
                    #pragma unroll
                    for(int r = 0; r < 8; r++){
                        float p = __builtin_amdgcn_exp2f(fminf(s[h * 8 + r], 15.f));
                        pf[r] = p; ls += p;
                    }
                    lp += ls;
                    unsigned x0 = __builtin_bit_cast(unsigned, __builtin_amdgcn_cvt_pkrtz(pf[0], pf[1]));
                    unsigned x1 = __builtin_bit_cast(unsigned, __builtin_amdgcn_cvt_pkrtz(pf[2], pf[3]));
                    unsigned y0 = __builtin_bit_cast(unsigned, __builtin_amdgcn_cvt_pkrtz(pf[4], pf[5]));
                    unsigned y1 = __builtin_bit_cast(unsigned, __builtin_amdgcn_cvt_pkrtz(pf[6], pf[7]));
                    asm("v_permlane32_swap_b32 %0, %1" : "+v"(x0), "+v"(y0));
                    asm("v_permlane32_swap_b32 %0, %1" : "+v"(x1), "+v"(y1));
                    u32x4 pw = {x0, x1, y0, y1};
                    half8 pa = __builtin_bit_cast(half8, pw);
                    __builtin_amdgcn_s_setprio(1);
                    #pragma unroll
                    for(int dt = 0; dt < 2; dt++){
                        half8 vb = *(const half8*)&Vb[(dt * 32 + l31) * LDW + kt * 32 + h * 16 + hi * 8];
                        o[dt] = __builtin_amdgcn_mfma_f32_32x32x16_f16(pa, vb, o[dt], 0, 0, 0);
                    }
                    __builtin_amdgcn_s_setprio(0);
                }
            }
            // staging bookkeeping: after slot0 compute write T(2jp+2) + load T(2jp+3);
            // after slot1 compute write T(2jp+3) + load T(2jp+4). Buffer cur^1 was fully
            // consumed before the previous pair's barrier -> write is race-free.
            if(jp < 7){
                f16* wb = &KV[(cur ^ 1) * BUF + slot * SLOT];
                #pragma unroll
                for(int i = 0; i < 4; i++) *(half8*)(wb + loff[i]) = pre[i];
                if(slot == 0 || jp < 6){
                    #pragma unroll
                    for(int i = 0; i < 4; i++){ pre[i] = *(const half8*)gsrc[i]; gsrc[i] += (i < 2) ? 4096 : 64; }
                }
            }
        }
        if(jp < 7) __syncthreads();
        cur ^= 1;
    }
    // row sums: lanes l and l+32 hold the same qrow
    {
        float v = lp + __shfl_xor(lp, 32);
        if(hi == 0){
            int row = qrow0 + l31;
            lw[kq * 16384 + row] = v;
            lred[w][l31] = __builtin_amdgcn_rcpf(v);
        }
    }
    // O layout: lane holds d = dt*32+l31; qrow = (r&3)+8*(r>>2)+4*hi
    #pragma unroll
    for(int r = 0; r < 16; r++){
        int qrl = (r & 3) + 8 * (r >> 2) + 4 * hi;
        float inv = lred[w][qrl];
        int row = qrow0 + qrl;
        #pragma unroll
        for(int dt = 0; dt < 2; dt++)
            Oph[kq * 1048576 + row * 64 + dt * 32 + l31] = (f16)(o[dt][r] * inv);
    }
}

// ---------------- K4: weighted merge of 4 normalized partials, W4 projection + bias + residual ----------------
__global__ __launch_bounds__(256) void k_merge(
    const f16* __restrict__ Oph, const float* __restrict__ lw,
    const float* __restrict__ w4, const float* __restrict__ b4,
    const float* __restrict__ x, float* __restrict__ out){
    __shared__ f16 Om[64 * LDW];
    __shared__ f16 wT[64 * LDW];
    __shared__ float b4f[64];
    int t = threadIdx.x;
    int rb = blockIdx.x * 64;
    for(int i = t; i < 4096; i += 256){
        int k = i >> 6, n = i & 63;
        wT[n * LDW + k] = (f16)w4[i];
    }
    if(t < 64) b4f[t] = b4[t];
    for(int i = t; i < 512; i += 256){
        int row = i >> 3, c8 = i & 7;
        int gr = rb + row;
        float num[8] = {0.f,0.f,0.f,0.f,0.f,0.f,0.f,0.f};
        float den = 0.f;
        #pragma unroll
        for(int s = 0; s < 4; s++){
            float li = lw[s * 16384 + gr];
            half8 ov = *(const half8*)&Oph[s * 1048576 + gr * 64 + c8 * 8];
            #pragma unroll
            for(int j = 0; j < 8; j++) num[j] += li * (float)ov[j];
            den += li;
        }
        float invd = 1.f / den;
        #pragma unroll
        for(int j = 0; j < 8; j++) Om[row * LDW + c8 * 8 + j] = (f16)(num[j] * invd);
    }
    __syncthreads();
    int w = t >> 6, lane = t & 63, quad = lane >> 4, l15 = lane & 15;
    half8 a[2];
    #pragma unroll
    for(int kc = 0; kc < 2; kc++)
        a[kc] = *(half8*)&Om[(w * 16 + l15) * LDW + kc * 32 + quad * 8];
    #pragma unroll
    for(int nt = 0; nt < 4; nt++){
        f32x4 y = {0.f, 0.f, 0.f, 0.f};
        #pragma unroll
        for(int kc = 0; kc < 2; kc++){
            half8 bfr = *(half8*)&wT[(nt * 16 + l15) * LDW + kc * 32 + quad * 8];
            y = __builtin_amdgcn_mfma_f32_16x16x32_f16(a[kc], bfr, y, 0, 0, 0);
        }
        #pragma unroll
        for(int r = 0; r < 4; r++){
            int row = rb + w * 16 + quad * 4 + r;
            int col = nt * 16 + l15;
            out[row * 64 + col] = y[r] + b4f[col] + x[row * 64 + col];
        }
    }
}

extern "C" void kernel_launch(void* const* d_in, const int* in_sizes, int n_in,
                              void* d_out, int out_size, void* d_ws, size_t ws_size,
                              hipStream_t stream){
    (void)in_sizes; (void)n_in; (void)out_size; (void)ws_size;
    const float* x  = (const float*)d_in[0];
    const float* w1 = (const float*)d_in[1];
    const float* w2 = (const float*)d_in[2];
    const float* w3 = (const float*)d_in[3];
    const float* w4 = (const float*)d_in[4];
    const float* b1 = (const float*)d_in[5];
    const float* b2 = (const float*)d_in[6];
    const float* b3 = (const float*)d_in[7];
    const float* b4 = (const float*)d_in[8];
    const float* gm = (const float*)d_in[9];
    const float* bt = (const float*)d_in[10];
    char* ws = (char*)d_ws;
    f16* Q    = (f16*)(ws);
    f16* Kx   = (f16*)(ws + (size_t)(2u << 20));
    f16* Vt   = (f16*)(ws + (size_t)(4u << 20));
    float* part = (float*)(ws + (size_t)(6u << 20));                         // 256 x 128 f32 = 128KB
    f16* Oph  = (f16*)(ws + (size_t)(8u << 20));                             // 4 x 2MB (f16, normalized)
    float* lwp = (float*)(ws + (size_t)(24u << 20));                         // 4 x 64KB

    hipLaunchKernelGGL(k_bnstats, dim3(256), dim3(256), 0, stream, x, part);
    hipLaunchKernelGGL(k_qkv,     dim3(256), dim3(256), 0, stream, x, w1, w2, w3, b1, b2, b3, gm, bt, part, Q, Kx, Vt);
    hipLaunchKernelGGL(k_attn,    dim3(512), dim3(256), 0, stream, Q, Kx, Vt, Oph, lwp);
    hipLaunchKernelGGL(k_merge,   dim3(256), dim3(256), 0, stream, Oph, lwp, w4, b4, x, (float*)d_out);
}